// Round 1
// baseline (971.493 us; speedup 1.0000x reference)
//
#include <hip/hip_runtime.h>
#include <hip/hip_bf16.h>

#define BH_B 4
#define SEQ 1024
#define HEADS 16
#define HDIM 64
#define EMB 1024
#define NREL 1025   // 2*512+1
#define TQ 8        // q rows per attention block
#define RSP 1028    // padded RS/PR row stride

static __device__ __forceinline__ float wave_max_f(float v) {
#pragma unroll
    for (int o = 32; o > 0; o >>= 1) v = fmaxf(v, __shfl_xor(v, o));
    return v;
}
static __device__ __forceinline__ float wave_sum_f(float v) {
#pragma unroll
    for (int o = 32; o > 0; o >>= 1) v += __shfl_xor(v, o);
    return v;
}

// ---------------------------------------------------------------------------
// Kernel 1: per-head linear projections.
// grid.x = B*L rows, grid.y = 0/1/2 (q/k/v). q is scaled by 0.125 (softmax /8
// folded in; both score terms are linear in q).
// q,v -> [bh][l][d]; k -> [bh][d][l] (transposed for coalesced QK dots).
// ---------------------------------------------------------------------------
__global__ __launch_bounds__(256) void sa_proj_kernel(
    const float* __restrict__ qin, const float* __restrict__ kin,
    const float* __restrict__ vin,
    const float* __restrict__ Wq, const float* __restrict__ bq,
    const float* __restrict__ Wk, const float* __restrict__ bk,
    const float* __restrict__ Wv, const float* __restrict__ bv,
    float* __restrict__ qp, float* __restrict__ ktp, float* __restrict__ vp) {
    __shared__ float xs[EMB];
    __shared__ float Wt[64 * 65];  // W transposed [e][d], padded
    const int t = threadIdx.x;
    const int row = blockIdx.x;          // b*L + l
    const int which = blockIdx.y;        // 0=q 1=k 2=v
    const float* x = (which == 0) ? qin : (which == 1) ? kin : vin;
    const float* W = (which == 0) ? Wq : (which == 1) ? Wk : Wv;
    const float* bias = (which == 0) ? bq : (which == 1) ? bk : bv;

    for (int i = t; i < EMB; i += 256) xs[i] = x[(size_t)row * EMB + i];
    for (int i = t; i < 64 * 64; i += 256) {
        int dd = i >> 6, ee = i & 63;
        Wt[ee * 65 + dd] = W[i];
    }
    __syncthreads();

    const int b = row >> 10, l = row & 1023;
    for (int i = t; i < EMB; i += 256) {
        const int h = i >> 6, dd = i & 63;
        float acc = bias[dd];
#pragma unroll
        for (int e = 0; e < 64; ++e) acc += xs[h * 64 + e] * Wt[e * 65 + dd];
        const size_t bh = (size_t)b * HEADS + h;
        if (which == 0) {
            qp[(bh * SEQ + l) * HDIM + dd] = acc * 0.125f;
        } else if (which == 1) {
            ktp[(bh * HDIM + dd) * SEQ + l] = acc;
        } else {
            vp[(bh * SEQ + l) * HDIM + dd] = acc;
        }
    }
}

// ---------------------------------------------------------------------------
// Kernel 2: transpose rel_k_table [1025][64] -> relk_t [64][1025]
// ---------------------------------------------------------------------------
__global__ __launch_bounds__(256) void sa_relkT_kernel(const float* __restrict__ relk,
                                                       float* __restrict__ relk_t) {
    int i = blockIdx.x * 256 + threadIdx.x;
    if (i < NREL * 64) {
        int r = i >> 6, d = i & 63;
        relk_t[d * NREL + r] = relk[i];
    }
}

// ---------------------------------------------------------------------------
// Kernel 3: fused attention. One block = 8 q rows of one (b,h).
// Phases: B) RS[qq][r]=q.relk[r]  C) S=QK(+mask)+RS gather  D) softmax (+
// clipped-tail partial sums)  E) PR[qq][r] (inverse rel map of p)
// F) out = (p@V + PR@relv) * inv
// ---------------------------------------------------------------------------
__global__ __launch_bounds__(256) void sa_attn_kernel(
    const float* __restrict__ qp, const float* __restrict__ ktp,
    const float* __restrict__ vp, const int* __restrict__ mask,
    const float* __restrict__ relk_t, const float* __restrict__ relv,
    float* __restrict__ ao) {
    __shared__ float qs[TQ * 64];
    __shared__ float S[TQ * SEQ];      // scores -> p -> reduction scratch
    __shared__ float RS[TQ * RSP];     // rel scores -> PR
    __shared__ float redA[4], redB[4], redC[4], redD[4];
    __shared__ float invS[TQ], lowS[TQ], highS[TQ];

    const int t = threadIdx.x;
    const int lane = t & 63, w = t >> 6;
    const int bid = blockIdx.x;
    const int bh = bid >> 7;           // 128 q-tiles per (b,h)
    const int q0 = (bid & 127) * TQ;
    const int b = bh >> 4, h = bh & 15;

    // Phase A: load 8 q rows (contiguous 512 floats)
    for (int i = t; i < TQ * 64; i += 256)
        qs[i] = qp[((size_t)bh * SEQ + q0) * HDIM + i];
    __syncthreads();

    // Phase B: RS[qq][r] = sum_d q[qq][d] * relk_t[d][r], r = t + 256c
    {
        float acc[TQ][4];
#pragma unroll
        for (int qq = 0; qq < TQ; ++qq)
#pragma unroll
            for (int c = 0; c < 4; ++c) acc[qq][c] = 0.f;
        for (int d = 0; d < 64; ++d) {
            const float* rrow = relk_t + d * NREL + t;
            float r0 = rrow[0], r1 = rrow[256], r2 = rrow[512], r3 = rrow[768];
#pragma unroll
            for (int qq = 0; qq < TQ; ++qq) {
                float qd = qs[qq * 64 + d];
                acc[qq][0] += qd * r0; acc[qq][1] += qd * r1;
                acc[qq][2] += qd * r2; acc[qq][3] += qd * r3;
            }
        }
#pragma unroll
        for (int qq = 0; qq < TQ; ++qq) {
            RS[qq * RSP + t] = acc[qq][0];
            RS[qq * RSP + t + 256] = acc[qq][1];
            RS[qq * RSP + t + 512] = acc[qq][2];
            RS[qq * RSP + t + 768] = acc[qq][3];
        }
        if (t < TQ) {  // r = 1024 tail
            float a = 0.f;
            for (int d = 0; d < 64; ++d) a += qs[t * 64 + d] * relk_t[d * NREL + 1024];
            RS[t * RSP + 1024] = a;
        }
    }
    __syncthreads();

    // Phase C: QK dots (k = 4t..4t+3), mask, add RS gather, store S
    {
        float acc[TQ][4];
#pragma unroll
        for (int qq = 0; qq < TQ; ++qq)
#pragma unroll
            for (int c = 0; c < 4; ++c) acc[qq][c] = 0.f;
        const float* ktb = ktp + (size_t)bh * HDIM * SEQ + 4 * t;
        for (int d = 0; d < 64; ++d) {
            float4 kv = *(const float4*)(ktb + d * SEQ);
#pragma unroll
            for (int qq = 0; qq < TQ; ++qq) {
                float qd = qs[qq * 64 + d];
                acc[qq][0] += qd * kv.x; acc[qq][1] += qd * kv.y;
                acc[qq][2] += qd * kv.z; acc[qq][3] += qd * kv.w;
            }
        }
        const int kbase = 4 * t;
#pragma unroll
        for (int qq = 0; qq < TQ; ++qq) {
            const int q = q0 + qq;
            int4 mk = *(const int4*)(mask + ((size_t)b * SEQ + q) * SEQ + kbase);
            float s0 = (mk.x == 0) ? -1e20f : acc[qq][0];
            float s1 = (mk.y == 0) ? -1e20f : acc[qq][1];
            float s2 = (mk.z == 0) ? -1e20f : acc[qq][2];
            float s3 = (mk.w == 0) ? -1e20f : acc[qq][3];
            int r0 = min(512, max(-512, kbase + 0 - q)) + 512;
            int r1 = min(512, max(-512, kbase + 1 - q)) + 512;
            int r2 = min(512, max(-512, kbase + 2 - q)) + 512;
            int r3 = min(512, max(-512, kbase + 3 - q)) + 512;
            s0 += RS[qq * RSP + r0]; s1 += RS[qq * RSP + r1];
            s2 += RS[qq * RSP + r2]; s3 += RS[qq * RSP + r3];
            float4 sv = make_float4(s0, s1, s2, s3);
            *(float4*)&S[qq * SEQ + kbase] = sv;
        }
    }
    __syncthreads();

    // Phase D: softmax per row; also masked tail sums for clipped rel index
    for (int qq = 0; qq < TQ; ++qq) {
        const int q = q0 + qq;
        const int kb = 4 * t;
        float4 sv = *(float4*)&S[qq * SEQ + kb];
        float m4 = fmaxf(fmaxf(sv.x, sv.y), fmaxf(sv.z, sv.w));
        m4 = wave_max_f(m4);
        if (lane == 0) redA[w] = m4;
        __syncthreads();
        float mx = fmaxf(fmaxf(redA[0], redA[1]), fmaxf(redA[2], redA[3]));
        float4 e;
        e.x = __expf(sv.x - mx); e.y = __expf(sv.y - mx);
        e.z = __expf(sv.z - mx); e.w = __expf(sv.w - mx);
        *(float4*)&S[qq * SEQ + kb] = e;
        float lsum = e.x + e.y + e.z + e.w;
        float llow = 0.f, lhigh = 0.f;
        llow += (kb + 0 <= q - 512) ? e.x : 0.f;
        llow += (kb + 1 <= q - 512) ? e.y : 0.f;
        llow += (kb + 2 <= q - 512) ? e.z : 0.f;
        llow += (kb + 3 <= q - 512) ? e.w : 0.f;
        lhigh += (kb + 0 >= q + 512) ? e.x : 0.f;
        lhigh += (kb + 1 >= q + 512) ? e.y : 0.f;
        lhigh += (kb + 2 >= q + 512) ? e.z : 0.f;
        lhigh += (kb + 3 >= q + 512) ? e.w : 0.f;
        lsum = wave_sum_f(lsum); llow = wave_sum_f(llow); lhigh = wave_sum_f(lhigh);
        if (lane == 0) { redB[w] = lsum; redC[w] = llow; redD[w] = lhigh; }
        __syncthreads();
        if (t == 0) {
            float ss = redB[0] + redB[1] + redB[2] + redB[3];
            invS[qq] = 1.f / ss;
            lowS[qq] = redC[0] + redC[1] + redC[2] + redC[3];
            highS[qq] = redD[0] + redD[1] + redD[2] + redD[3];
        }
    }
    __syncthreads();

    // Phase E: PR[qq][r] = sum of p over {k : idx(q,k)=r}  (RS reused as PR)
#pragma unroll
    for (int qq = 0; qq < TQ; ++qq) {
        const int q = q0 + qq;
#pragma unroll
        for (int c = 0; c < 4; ++c) {
            const int r = t + 256 * c;
            float val;
            if (r == 0) {
                val = lowS[qq];
            } else {
                const int k = q + r - 512;
                val = (k >= 0 && k < SEQ) ? S[qq * SEQ + k] : 0.f;
            }
            RS[qq * RSP + r] = val;
        }
    }
    if (t < TQ) RS[t * RSP + 1024] = highS[t];
    __syncthreads();

    // Phase F: out[qq][d] = inv * (sum_k p*v + sum_r PR*relv)
    {
        const int d4 = (t & 15) * 4;
        const int kc = t >> 4;  // 16 groups x 64 k each
        float acc[TQ][4];
#pragma unroll
        for (int qq = 0; qq < TQ; ++qq)
#pragma unroll
            for (int c = 0; c < 4; ++c) acc[qq][c] = 0.f;
        const float* vb = vp + (size_t)bh * SEQ * HDIM;
        for (int k0 = kc * 64; k0 < kc * 64 + 64; k0 += 4) {
            float4 p4[TQ];
#pragma unroll
            for (int qq = 0; qq < TQ; ++qq) p4[qq] = *(float4*)&S[qq * SEQ + k0];
#pragma unroll
            for (int j = 0; j < 4; ++j) {
                float4 v4 = *(const float4*)(vb + (size_t)(k0 + j) * HDIM + d4);
#pragma unroll
                for (int qq = 0; qq < TQ; ++qq) {
                    float pk = (j == 0) ? p4[qq].x : (j == 1) ? p4[qq].y
                                : (j == 2) ? p4[qq].z : p4[qq].w;
                    acc[qq][0] += pk * v4.x; acc[qq][1] += pk * v4.y;
                    acc[qq][2] += pk * v4.z; acc[qq][3] += pk * v4.w;
                }
            }
        }
        for (int r0 = kc * 64; r0 < kc * 64 + 64; r0 += 4) {
            float4 p4[TQ];
#pragma unroll
            for (int qq = 0; qq < TQ; ++qq) p4[qq] = *(float4*)&RS[qq * RSP + r0];
#pragma unroll
            for (int j = 0; j < 4; ++j) {
                float4 v4 = *(const float4*)(relv + (size_t)(r0 + j) * HDIM + d4);
#pragma unroll
                for (int qq = 0; qq < TQ; ++qq) {
                    float pk = (j == 0) ? p4[qq].x : (j == 1) ? p4[qq].y
                                : (j == 2) ? p4[qq].z : p4[qq].w;
                    acc[qq][0] += pk * v4.x; acc[qq][1] += pk * v4.y;
                    acc[qq][2] += pk * v4.z; acc[qq][3] += pk * v4.w;
                }
            }
        }
        if (kc == 15) {  // r = 1024 tail
            float4 v4 = *(const float4*)(relv + (size_t)1024 * HDIM + d4);
#pragma unroll
            for (int qq = 0; qq < TQ; ++qq) {
                float pk = RS[qq * RSP + 1024];
                acc[qq][0] += pk * v4.x; acc[qq][1] += pk * v4.y;
                acc[qq][2] += pk * v4.z; acc[qq][3] += pk * v4.w;
            }
        }
        __syncthreads();  // all S (p) reads done before reuse as scratch
        float* fred = S;  // [16 kc][8 qq][64 d]
#pragma unroll
        for (int qq = 0; qq < TQ; ++qq)
            *(float4*)&fred[kc * 512 + qq * 64 + d4] =
                make_float4(acc[qq][0], acc[qq][1], acc[qq][2], acc[qq][3]);
        __syncthreads();
        for (int o = t; o < TQ * 64; o += 256) {
            const int qq = o >> 6, d = o & 63;
            float ssum = 0.f;
#pragma unroll
            for (int k = 0; k < 16; ++k) ssum += fred[k * 512 + o];
            const float val = ssum * invS[qq];
            ao[(((size_t)b * SEQ + q0 + qq) * HEADS + h) * HDIM + d] = val;
        }
    }
}

// ---------------------------------------------------------------------------
// Kernel 4: final FC.  out[m][n] = sum_k A[m][k]*Wfc[n][k] + bfc[n]
// M=4096 N=1024 K=1024, 128x128x8 tile, 8x8 per thread.
// ---------------------------------------------------------------------------
__global__ __launch_bounds__(256) void sa_fc_kernel(
    const float* __restrict__ A, const float* __restrict__ W,
    const float* __restrict__ bias, float* __restrict__ out) {
    __shared__ float As[8][132];
    __shared__ float Bs[8][132];
    const int t = threadIdx.x;
    const int m0 = blockIdx.x * 128, n0 = blockIdx.y * 128;
    const int lm = t >> 1, lk4 = (t & 1) * 4;
    const int ty = t >> 4, tx = t & 15;
    float acc[8][8];
#pragma unroll
    for (int i = 0; i < 8; ++i)
#pragma unroll
        for (int j = 0; j < 8; ++j) acc[i][j] = 0.f;

    for (int k0 = 0; k0 < 1024; k0 += 8) {
        float4 av = *(const float4*)(A + (size_t)(m0 + lm) * 1024 + k0 + lk4);
        float4 bv = *(const float4*)(W + (size_t)(n0 + lm) * 1024 + k0 + lk4);
        __syncthreads();
        As[lk4 + 0][lm] = av.x; As[lk4 + 1][lm] = av.y;
        As[lk4 + 2][lm] = av.z; As[lk4 + 3][lm] = av.w;
        Bs[lk4 + 0][lm] = bv.x; Bs[lk4 + 1][lm] = bv.y;
        Bs[lk4 + 2][lm] = bv.z; Bs[lk4 + 3][lm] = bv.w;
        __syncthreads();
#pragma unroll
        for (int kk = 0; kk < 8; ++kk) {
            float4 a0 = *(float4*)&As[kk][ty * 8];
            float4 a1 = *(float4*)&As[kk][ty * 8 + 4];
            float4 b0 = *(float4*)&Bs[kk][tx * 8];
            float4 b1 = *(float4*)&Bs[kk][tx * 8 + 4];
            float a[8] = {a0.x, a0.y, a0.z, a0.w, a1.x, a1.y, a1.z, a1.w};
            float bb[8] = {b0.x, b0.y, b0.z, b0.w, b1.x, b1.y, b1.z, b1.w};
#pragma unroll
            for (int i = 0; i < 8; ++i)
#pragma unroll
                for (int j = 0; j < 8; ++j) acc[i][j] += a[i] * bb[j];
        }
    }
#pragma unroll
    for (int i = 0; i < 8; ++i) {
        const size_t m = m0 + ty * 8 + i;
#pragma unroll
        for (int j = 0; j < 8; ++j) {
            const int n = n0 + tx * 8 + j;
            out[m * 1024 + n] = acc[i][j] + bias[n];
        }
    }
}

extern "C" void kernel_launch(void* const* d_in, const int* in_sizes, int n_in,
                              void* d_out, int out_size, void* d_ws, size_t ws_size,
                              hipStream_t stream) {
    const float* query = (const float*)d_in[0];
    const float* key = (const float*)d_in[1];
    const float* value = (const float*)d_in[2];
    const int* mask = (const int*)d_in[3];
    const float* Wq = (const float*)d_in[4];
    const float* bq = (const float*)d_in[5];
    const float* Wk = (const float*)d_in[6];
    const float* bk = (const float*)d_in[7];
    const float* Wv = (const float*)d_in[8];
    const float* bv = (const float*)d_in[9];
    const float* Wfc = (const float*)d_in[10];
    const float* bfc = (const float*)d_in[11];
    const float* relk = (const float*)d_in[12];
    const float* relv = (const float*)d_in[13];
    float* out = (float*)d_out;

    float* ws = (float*)d_ws;
    const size_t TEN = (size_t)BH_B * HEADS * SEQ * HDIM;  // 4,194,304
    float* qp = ws;
    float* ktp = qp + TEN;
    float* vp = ktp + TEN;
    float* ao = vp + TEN;
    float* relk_t = ao + TEN;  // 64*1025 floats

    sa_proj_kernel<<<dim3(BH_B * SEQ, 3), 256, 0, stream>>>(
        query, key, value, Wq, bq, Wk, bk, Wv, bv, qp, ktp, vp);
    sa_relkT_kernel<<<(NREL * 64 + 255) / 256, 256, 0, stream>>>(relk, relk_t);
    sa_attn_kernel<<<BH_B * HEADS * (SEQ / TQ), 256, 0, stream>>>(
        qp, ktp, vp, mask, relk_t, relv, ao);
    sa_fc_kernel<<<dim3(BH_B * SEQ / 128, EMB / 128), 256, 0, stream>>>(
        ao, Wfc, bfc, out);
}

// Round 2
// 549.336 us; speedup vs baseline: 1.7685x; 1.7685x over previous
//
#include <hip/hip_runtime.h>
#include <hip/hip_bf16.h>

#define SEQ 1024
#define HEADS 16
#define HDIM 64
#define EMB 1024
#define TQ 32            // q rows per attention block
#define RSP 1032         // padded LDS row stride (bf16 elems), 16B-aligned rows
#define RELK_ROWS 1040   // 1025 real + pad
#define RELV_STRIDE 1032 // relv^T padded col stride

typedef __bf16 bf16x8 __attribute__((ext_vector_type(8)));
typedef float floatx4 __attribute__((ext_vector_type(4)));

static __device__ __forceinline__ unsigned short f2bu(float f) {
    unsigned u = __builtin_bit_cast(unsigned, f);
    u = (u + 0x7fffu + ((u >> 16) & 1u)) >> 16;   // RNE
    return (unsigned short)u;
}
static __device__ __forceinline__ float b2f(unsigned short u) {
    unsigned v = ((unsigned)u) << 16;
    return __builtin_bit_cast(float, v);
}

// ---------------------------------------------------------------------------
// Kernel 1: per-head projections, fp32 math -> bf16 outputs.
// grid (1024, 3): 4 rows per block; which = 0/1/2 -> q/k/v.
// qb,kb: [bh][l][64] bf16 (q scaled by 0.125); vtb: [bh][64][l] bf16.
// ---------------------------------------------------------------------------
__global__ __launch_bounds__(256) void sa_proj_kernel(
    const float* __restrict__ qin, const float* __restrict__ kin,
    const float* __restrict__ vin,
    const float* __restrict__ Wq, const float* __restrict__ bq,
    const float* __restrict__ Wk, const float* __restrict__ bk,
    const float* __restrict__ Wv, const float* __restrict__ bv,
    unsigned short* __restrict__ qb, unsigned short* __restrict__ kb,
    unsigned short* __restrict__ vtb) {
    __shared__ float xs[4 * 1056];    // [ri][h*66 + e]
    __shared__ float Wt[64 * 68];     // [e][d]
    const int t = threadIdx.x;
    const int row4 = blockIdx.x * 4;
    const int which = blockIdx.y;
    const float* x = (which == 0) ? qin : (which == 1) ? kin : vin;
    const float* W = (which == 0) ? Wq : (which == 1) ? Wk : Wv;
    const float* bias = (which == 0) ? bq : (which == 1) ? bk : bv;

    for (int i = t; i < 64 * 64; i += 256) {
        int d = i >> 6, e = i & 63;
        Wt[e * 68 + d] = W[i];
    }
    for (int i = t; i < 4 * 1024; i += 256) {
        int ri = i >> 10, j = i & 1023;
        int h = j >> 6, e = j & 63;
        xs[ri * 1056 + h * 66 + e] = x[(size_t)(row4 + ri) * EMB + j];
    }
    __syncthreads();

    const int h = t >> 4;
    const int dd0 = (t & 15) * 4;
    float acc[4][4];
#pragma unroll
    for (int ri = 0; ri < 4; ++ri)
#pragma unroll
        for (int j = 0; j < 4; ++j) acc[ri][j] = 0.f;

#pragma unroll 8
    for (int e = 0; e < 64; ++e) {
        float4 wv = *(const float4*)&Wt[e * 68 + dd0];
        float xv0 = xs[0 * 1056 + h * 66 + e];
        float xv1 = xs[1 * 1056 + h * 66 + e];
        float xv2 = xs[2 * 1056 + h * 66 + e];
        float xv3 = xs[3 * 1056 + h * 66 + e];
        acc[0][0] += xv0 * wv.x; acc[0][1] += xv0 * wv.y; acc[0][2] += xv0 * wv.z; acc[0][3] += xv0 * wv.w;
        acc[1][0] += xv1 * wv.x; acc[1][1] += xv1 * wv.y; acc[1][2] += xv1 * wv.z; acc[1][3] += xv1 * wv.w;
        acc[2][0] += xv2 * wv.x; acc[2][1] += xv2 * wv.y; acc[2][2] += xv2 * wv.z; acc[2][3] += xv2 * wv.w;
        acc[3][0] += xv3 * wv.x; acc[3][1] += xv3 * wv.y; acc[3][2] += xv3 * wv.z; acc[3][3] += xv3 * wv.w;
    }
    float bv4[4];
#pragma unroll
    for (int j = 0; j < 4; ++j) bv4[j] = bias[dd0 + j];
#pragma unroll
    for (int ri = 0; ri < 4; ++ri) {
        const int row = row4 + ri;
        const int b = row >> 10, l = row & 1023;
        const int bh = b * HEADS + h;
#pragma unroll
        for (int j = 0; j < 4; ++j) {
            float v = acc[ri][j] + bv4[j];
            if (which == 0) {
                qb[((size_t)bh * SEQ + l) * HDIM + dd0 + j] = f2bu(v * 0.125f);
            } else if (which == 1) {
                kb[((size_t)bh * SEQ + l) * HDIM + dd0 + j] = f2bu(v);
            } else {
                vtb[((size_t)bh * HDIM + dd0 + j) * SEQ + l] = f2bu(v);
            }
        }
    }
}

// ---------------------------------------------------------------------------
// Kernel 2: prep — bf16 conversions / transposes with zero padding.
//  Wfc_b [1024][1024]; relk_b [1040][64]; relvT [64][1032].
// ---------------------------------------------------------------------------
#define NW (1024 * 1024)
#define NRK (RELK_ROWS * 64)
#define NRV (64 * RELV_STRIDE)
__global__ __launch_bounds__(256) void sa_prep_kernel(
    const float* __restrict__ Wfc, const float* __restrict__ relk,
    const float* __restrict__ relv, unsigned short* __restrict__ wfcb,
    unsigned short* __restrict__ relkb, unsigned short* __restrict__ relvtb) {
    int i = blockIdx.x * 256 + threadIdx.x;
    if (i < NW) {
        wfcb[i] = f2bu(Wfc[i]);
    } else if (i < NW + NRK) {
        int j = i - NW;
        int r = j >> 6, d = j & 63;
        relkb[j] = (r <= 1024) ? f2bu(relk[r * 64 + d]) : 0;
    } else if (i < NW + NRK + NRV) {
        int j = i - NW - NRK;
        int d = j / RELV_STRIDE, c = j - d * RELV_STRIDE;
        relvtb[j] = (c <= 1024) ? f2bu(relv[c * 64 + d]) : 0;
    }
}

// ---------------------------------------------------------------------------
// Kernel 3: MFMA attention. 512 threads (8 waves), one block = 32 q-rows of
// one (b,h). Wave w: Mtile = w>>2 (16 rows), sub = w&3 (k/r/d chunk).
// Phases: B) RS = Q@relk^T -> bf16 LDS. C) S = Q@K^T (regs) + RS gather +
// mask; row max. D) exp, sums (+clip tails), P -> bf16 LDS. E) PR shift-build.
// F) O = P@V^T + PR@relv^T (+rank-1 r=1024 tail), scale, store bf16.
// ---------------------------------------------------------------------------
__global__ __launch_bounds__(512, 2) void sa_attn_kernel(
    const unsigned short* __restrict__ qb, const unsigned short* __restrict__ kb,
    const unsigned short* __restrict__ vtb, const int* __restrict__ mask,
    const unsigned short* __restrict__ relkb, const unsigned short* __restrict__ relvtb,
    unsigned short* __restrict__ aob) {
    __shared__ unsigned short RS[TQ * RSP];   // rel scores, then PR
    __shared__ unsigned short Pb[TQ * RSP];   // p (unnormalized) bf16
    __shared__ float wmax[4 * 32], wsum[4 * 32], wlow[4 * 32], whigh[4 * 32];
    __shared__ float invS[32], lowS[32], highS[32];

    const int tid = threadIdx.x;
    const int w = tid >> 6, lane = tid & 63;
    const int quad = lane >> 4, l16 = lane & 15;
    const int Mtile = w >> 2, sub = w & 3;
    const int rowbase = Mtile * 16;

    const int bid = blockIdx.x;
    const int bh = bid >> 5;
    const int q0 = (bid & 31) * TQ;
    const int b = bh >> 4, h = bh & 15;

    // Preload this wave's Q A-fragments (rows rowbase..rowbase+15, K=64)
    bf16x8 aq[2];
    {
        const unsigned short* qrow =
            qb + ((size_t)(bh * SEQ + q0 + rowbase + l16)) * HDIM;
#pragma unroll
        for (int ks = 0; ks < 2; ++ks)
            aq[ks] = *reinterpret_cast<const bf16x8*>(qrow + ks * 32 + quad * 8);
    }

    // ---- Phase B: RS[row][r] = (Q @ relk^T), bf16 in LDS ----
    for (int rt = sub; rt < 65; rt += 4) {
        floatx4 acc = {0.f, 0.f, 0.f, 0.f};
#pragma unroll
        for (int ks = 0; ks < 2; ++ks) {
            bf16x8 bfrag = *reinterpret_cast<const bf16x8*>(
                relkb + ((size_t)(rt * 16 + l16)) * 64 + ks * 32 + quad * 8);
            acc = __builtin_amdgcn_mfma_f32_16x16x32_bf16(aq[ks], bfrag, acc, 0, 0, 0);
        }
        const int rcol = rt * 16 + l16;
        if (rcol <= 1024) {
#pragma unroll
            for (int i = 0; i < 4; ++i)
                RS[(rowbase + quad * 4 + i) * RSP + rcol] = f2bu(acc[i]);
        }
    }
    __syncthreads();

    // ---- Phase C: S = Q@K^T (regs), + RS gather + mask; running max ----
    floatx4 acc[16];
#pragma unroll
    for (int tt = 0; tt < 16; ++tt) acc[tt] = floatx4{0.f, 0.f, 0.f, 0.f};
    const int kbase = sub * 256;
#pragma unroll
    for (int tt = 0; tt < 16; ++tt) {
#pragma unroll
        for (int ks = 0; ks < 2; ++ks) {
            bf16x8 bfrag = *reinterpret_cast<const bf16x8*>(
                kb + ((size_t)(bh * SEQ + kbase + tt * 16 + l16)) * HDIM + ks * 32 + quad * 8);
            acc[tt] = __builtin_amdgcn_mfma_f32_16x16x32_bf16(aq[ks], bfrag, acc[tt], 0, 0, 0);
        }
    }
    float rmax[4] = {-3.0e38f, -3.0e38f, -3.0e38f, -3.0e38f};
#pragma unroll
    for (int tt = 0; tt < 16; ++tt) {
        const int k = kbase + tt * 16 + l16;
#pragma unroll
        for (int i = 0; i < 4; ++i) {
            const int row = rowbase + quad * 4 + i;
            const int q = q0 + row;
            int dist = k - q;
            int r = min(512, max(-512, dist)) + 512;
            float s = acc[tt][i] + b2f(RS[row * RSP + r]);
            int m = mask[(size_t)b * (SEQ * SEQ) + (size_t)q * SEQ + k];
            s = (m == 0) ? -1e20f : s;
            acc[tt][i] = s;
            rmax[i] = fmaxf(rmax[i], s);
        }
    }
#pragma unroll
    for (int i = 0; i < 4; ++i) {
#pragma unroll
        for (int o = 1; o < 16; o <<= 1) rmax[i] = fmaxf(rmax[i], __shfl_xor(rmax[i], o));
    }
    if (l16 == 0) {
#pragma unroll
        for (int i = 0; i < 4; ++i) wmax[sub * 32 + rowbase + quad * 4 + i] = rmax[i];
    }
    __syncthreads();

    // ---- Phase D: exp, sums (+clipped tails), P -> bf16 LDS ----
    float mx[4], ssum[4], slow[4], shigh[4];
#pragma unroll
    for (int i = 0; i < 4; ++i) {
        const int row = rowbase + quad * 4 + i;
        mx[i] = fmaxf(fmaxf(wmax[0 * 32 + row], wmax[1 * 32 + row]),
                      fmaxf(wmax[2 * 32 + row], wmax[3 * 32 + row]));
        ssum[i] = 0.f; slow[i] = 0.f; shigh[i] = 0.f;
    }
#pragma unroll
    for (int tt = 0; tt < 16; ++tt) {
        const int k = kbase + tt * 16 + l16;
#pragma unroll
        for (int i = 0; i < 4; ++i) {
            const int row = rowbase + quad * 4 + i;
            const int q = q0 + row;
            float p = __expf(acc[tt][i] - mx[i]);
            ssum[i] += p;
            slow[i] += (k - q <= -512) ? p : 0.f;
            shigh[i] += (k - q >= 512) ? p : 0.f;
            Pb[row * RSP + k] = f2bu(p);
        }
    }
#pragma unroll
    for (int i = 0; i < 4; ++i) {
#pragma unroll
        for (int o = 1; o < 16; o <<= 1) {
            ssum[i] += __shfl_xor(ssum[i], o);
            slow[i] += __shfl_xor(slow[i], o);
            shigh[i] += __shfl_xor(shigh[i], o);
        }
    }
    if (l16 == 0) {
#pragma unroll
        for (int i = 0; i < 4; ++i) {
            const int row = rowbase + quad * 4 + i;
            wsum[sub * 32 + row] = ssum[i];
            wlow[sub * 32 + row] = slow[i];
            whigh[sub * 32 + row] = shigh[i];
        }
    }
    __syncthreads();
    if (tid < 32) {
        float s = wsum[tid] + wsum[32 + tid] + wsum[64 + tid] + wsum[96 + tid];
        invS[tid] = 1.f / s;
        lowS[tid] = wlow[tid] + wlow[32 + tid] + wlow[64 + tid] + wlow[96 + tid];
        highS[tid] = whigh[tid] + whigh[32 + tid] + whigh[64 + tid] + whigh[96 + tid];
    }
    __syncthreads();

    // ---- Phase E: PR[row][c] (overwrites RS). c=0 -> low tail; interior
    // c in [1,1023]: k = q + c - 512 ----
    for (int rep = 0; rep < 64; ++rep) {
        const int idx = rep * 512 + tid;
        const int row = idx >> 10, c = idx & 1023;
        float val;
        if (c == 0) {
            val = lowS[row];
        } else {
            const int k = q0 + row + c - 512;
            val = (k >= 0 && k < SEQ) ? b2f(Pb[row * RSP + k]) : 0.f;
        }
        RS[row * RSP + c] = f2bu(val);
    }
    __syncthreads();

    // ---- Phase F: O = P@V^T + PR@relv^T (+ r=1024 rank-1), scale, store ----
    const int d0 = sub * 16;
    floatx4 accA = {0.f, 0.f, 0.f, 0.f};
    floatx4 accB = {0.f, 0.f, 0.f, 0.f};
#pragma unroll 4
    for (int ks = 0; ks < 32; ++ks) {
        bf16x8 ap = *reinterpret_cast<const bf16x8*>(
            &Pb[(rowbase + l16) * RSP + ks * 32 + quad * 8]);
        bf16x8 bv = *reinterpret_cast<const bf16x8*>(
            vtb + ((size_t)(bh * HDIM + d0 + l16)) * SEQ + ks * 32 + quad * 8);
        accA = __builtin_amdgcn_mfma_f32_16x16x32_bf16(ap, bv, accA, 0, 0, 0);
        bf16x8 ar = *reinterpret_cast<const bf16x8*>(
            &RS[(rowbase + l16) * RSP + ks * 32 + quad * 8]);
        bf16x8 br = *reinterpret_cast<const bf16x8*>(
            relvtb + (size_t)(d0 + l16) * RELV_STRIDE + ks * 32 + quad * 8);
        accB = __builtin_amdgcn_mfma_f32_16x16x32_bf16(ar, br, accB, 0, 0, 0);
    }
    // r = 1024 tail: O += highS[row] * relv[1024][d]
    {
        float rv = b2f(relvtb[(size_t)(d0 + l16) * RELV_STRIDE + 1024]);
#pragma unroll
        for (int i = 0; i < 4; ++i) {
            const int row = rowbase + quad * 4 + i;
            accB[i] += highS[row] * rv;
        }
    }
#pragma unroll
    for (int i = 0; i < 4; ++i) {
        const int row = rowbase + quad * 4 + i;
        const int q = q0 + row;
        float val = (accA[i] + accB[i]) * invS[row];
        aob[((size_t)(b * SEQ + q)) * EMB + h * HDIM + d0 + l16] = f2bu(val);
    }
}

// ---------------------------------------------------------------------------
// Kernel 4: FC MFMA GEMM. out[4096][1024] = ao_b @ Wfc_b^T + bfc (fp32 out).
// grid (128, 4); block 256 (4 waves). Block tile M=32, N=256.
// Wave: Mtile = w&1, 8 N-tiles at (w>>1)*8.
// ---------------------------------------------------------------------------
__global__ __launch_bounds__(256) void sa_fc_kernel(
    const unsigned short* __restrict__ A, const unsigned short* __restrict__ W,
    const float* __restrict__ bias, float* __restrict__ out) {
    const int t = threadIdx.x;
    const int w = t >> 6, lane = t & 63;
    const int quad = lane >> 4, l16 = lane & 15;
    const int m0 = blockIdx.x * 32 + (w & 1) * 16;
    const int n0 = blockIdx.y * 256 + (w >> 1) * 128;

    floatx4 acc[8];
#pragma unroll
    for (int j = 0; j < 8; ++j) acc[j] = floatx4{0.f, 0.f, 0.f, 0.f};

    for (int ks = 0; ks < 32; ++ks) {
        bf16x8 a = *reinterpret_cast<const bf16x8*>(
            A + ((size_t)(m0 + l16)) * EMB + ks * 32 + quad * 8);
#pragma unroll
        for (int j = 0; j < 8; ++j) {
            bf16x8 bfrag = *reinterpret_cast<const bf16x8*>(
                W + ((size_t)(n0 + j * 16 + l16)) * EMB + ks * 32 + quad * 8);
            acc[j] = __builtin_amdgcn_mfma_f32_16x16x32_bf16(a, bfrag, acc[j], 0, 0, 0);
        }
    }
#pragma unroll
    for (int j = 0; j < 8; ++j) {
        const int col = n0 + j * 16 + l16;
        const float bc = bias[col];
#pragma unroll
        for (int i = 0; i < 4; ++i) {
            const int row = m0 + quad * 4 + i;
            out[(size_t)row * EMB + col] = acc[j][i] + bc;
        }
    }
}

extern "C" void kernel_launch(void* const* d_in, const int* in_sizes, int n_in,
                              void* d_out, int out_size, void* d_ws, size_t ws_size,
                              hipStream_t stream) {
    const float* query = (const float*)d_in[0];
    const float* key = (const float*)d_in[1];
    const float* value = (const float*)d_in[2];
    const int* mask = (const int*)d_in[3];
    const float* Wq = (const float*)d_in[4];
    const float* bq = (const float*)d_in[5];
    const float* Wk = (const float*)d_in[6];
    const float* bk = (const float*)d_in[7];
    const float* Wv = (const float*)d_in[8];
    const float* bv = (const float*)d_in[9];
    const float* Wfc = (const float*)d_in[10];
    const float* bfc = (const float*)d_in[11];
    const float* relk = (const float*)d_in[12];
    const float* relv = (const float*)d_in[13];
    float* out = (float*)d_out;

    char* base = (char*)d_ws;
    const size_t MB = (size_t)1 << 20;
    unsigned short* qb = (unsigned short*)(base + 0 * MB);
    unsigned short* kb = (unsigned short*)(base + 8 * MB);
    unsigned short* vtb = (unsigned short*)(base + 16 * MB);
    unsigned short* aob = (unsigned short*)(base + 24 * MB);
    unsigned short* wfcb = (unsigned short*)(base + 32 * MB);
    unsigned short* relkb = (unsigned short*)(base + 34 * MB);
    unsigned short* relvtb = (unsigned short*)(base + 35 * MB);

    sa_proj_kernel<<<dim3(1024, 3), 256, 0, stream>>>(
        query, key, value, Wq, bq, Wk, bk, Wv, bv, qb, kb, vtb);
    sa_prep_kernel<<<(NW + NRK + NRV + 255) / 256, 256, 0, stream>>>(
        Wfc, relk, relv, wfcb, relkb, relvtb);
    sa_attn_kernel<<<4 * HEADS * (SEQ / TQ), 512, 0, stream>>>(
        qb, kb, vtb, mask, relkb, relvtb, aob);
    sa_fc_kernel<<<dim3(4096 / 32, 1024 / 256), 256, 0, stream>>>(
        aob, wfcb, bfc, out);
}

// Round 4
// 422.189 us; speedup vs baseline: 2.3011x; 1.3012x over previous
//
#include <hip/hip_runtime.h>
#include <hip/hip_bf16.h>

#define SEQ 1024
#define HEADS 16
#define HDIM 64
#define EMB 1024
#define TQ 16            // q rows per attention block
#define PBS 1032         // P buffer row stride (u16), 16B-aligned rows
#define RELK_ROWS 1040   // 1025 real + pad
#define RELV_STRIDE 1032 // relv^T padded col stride

typedef __bf16 bf16x8 __attribute__((ext_vector_type(8)));
typedef unsigned short u16x8 __attribute__((ext_vector_type(8)));
typedef float floatx4 __attribute__((ext_vector_type(4)));

static __device__ __forceinline__ unsigned short f2bu(float f) {
    unsigned u = __builtin_bit_cast(unsigned, f);
    u = (u + 0x7fffu + ((u >> 16) & 1u)) >> 16;   // RNE
    return (unsigned short)u;
}
static __device__ __forceinline__ float b2f(unsigned short u) {
    unsigned v = ((unsigned)u) << 16;
    return __builtin_bit_cast(float, v);
}

// ---------------------------------------------------------------------------
// Kernel 1: MFMA projections. grid (256, 3): blockIdx.x -> 16 rows,
// blockIdx.y = which (q/k/v). 256 thr = 4 waves; wave w -> heads w*4..w*4+3.
// q,k -> [bh][l][64] bf16 (q scaled 0.125); v -> vtb [bh][64][l] bf16.
// NOTE: depends on sa_prep_kernel having produced wqb/wkb/wvb — prep MUST be
// launched first (R3 bug: order was swapped -> poison weights -> absmax 0.32).
// ---------------------------------------------------------------------------
__global__ __launch_bounds__(256) void sa_proj_kernel(
    const float* __restrict__ qin, const float* __restrict__ kin,
    const float* __restrict__ vin,
    const unsigned short* __restrict__ wqb, const unsigned short* __restrict__ wkb,
    const unsigned short* __restrict__ wvb,
    const float* __restrict__ bq, const float* __restrict__ bk,
    const float* __restrict__ bv_,
    unsigned short* __restrict__ qb, unsigned short* __restrict__ kb,
    unsigned short* __restrict__ vtb) {
    const int t = threadIdx.x;
    const int w = t >> 6, lane = t & 63;
    const int quad = lane >> 4, l16 = lane & 15;
    const int which = blockIdx.y;
    const int r0 = blockIdx.x * 16;
    const int bidx = r0 >> 10;
    const int l0 = r0 & 1023;
    const float* x = (which == 0) ? qin : (which == 1) ? kin : vin;
    const unsigned short* Wb = (which == 0) ? wqb : (which == 1) ? wkb : wvb;
    const float* bias = (which == 0) ? bq : (which == 1) ? bk : bv_;

    // W fragments [dtile][ks], rows = out-dim d, cols = in-dim e
    bf16x8 wf[4][2];
#pragma unroll
    for (int dt = 0; dt < 4; ++dt)
#pragma unroll
        for (int ks = 0; ks < 2; ++ks)
            wf[dt][ks] = *(const bf16x8*)(Wb + (size_t)(dt * 16 + l16) * 64 + ks * 32 + quad * 8);

    if (which < 2) {
        float biasd[4];
#pragma unroll
        for (int dt = 0; dt < 4; ++dt) biasd[dt] = bias[dt * 16 + l16];
        const float sc = (which == 0) ? 0.125f : 1.0f;
        unsigned short* dst = (which == 0) ? qb : kb;
        for (int hh = 0; hh < 4; ++hh) {
            const int h = w * 4 + hh;
            bf16x8 xf[2];
#pragma unroll
            for (int ks = 0; ks < 2; ++ks) {
                const float* xp = x + (size_t)(r0 + l16) * EMB + h * 64 + ks * 32 + quad * 8;
                float4 lo = *(const float4*)xp;
                float4 hi = *(const float4*)(xp + 4);
                u16x8 px;
                px[0] = f2bu(lo.x); px[1] = f2bu(lo.y); px[2] = f2bu(lo.z); px[3] = f2bu(lo.w);
                px[4] = f2bu(hi.x); px[5] = f2bu(hi.y); px[6] = f2bu(hi.z); px[7] = f2bu(hi.w);
                xf[ks] = __builtin_bit_cast(bf16x8, px);
            }
            floatx4 acc[4];
#pragma unroll
            for (int dt = 0; dt < 4; ++dt) acc[dt] = floatx4{0.f, 0.f, 0.f, 0.f};
#pragma unroll
            for (int dt = 0; dt < 4; ++dt)
#pragma unroll
                for (int ks = 0; ks < 2; ++ks)
                    acc[dt] = __builtin_amdgcn_mfma_f32_16x16x32_bf16(xf[ks], wf[dt][ks], acc[dt], 0, 0, 0);
            const int bh = bidx * HEADS + h;
#pragma unroll
            for (int dt = 0; dt < 4; ++dt)
#pragma unroll
                for (int i = 0; i < 4; ++i) {
                    const int lr = l0 + quad * 4 + i;
                    float val = (acc[dt][i] + biasd[dt]) * sc;
                    dst[((size_t)bh * SEQ + lr) * 64 + dt * 16 + l16] = f2bu(val);
                }
        }
    } else {
        float biasv[4][4];
#pragma unroll
        for (int dt = 0; dt < 4; ++dt)
#pragma unroll
            for (int i = 0; i < 4; ++i) biasv[dt][i] = bias[dt * 16 + quad * 4 + i];
        for (int hh = 0; hh < 4; ++hh) {
            const int h = w * 4 + hh;
            bf16x8 xf[2];
#pragma unroll
            for (int ks = 0; ks < 2; ++ks) {
                const float* xp = x + (size_t)(r0 + l16) * EMB + h * 64 + ks * 32 + quad * 8;
                float4 lo = *(const float4*)xp;
                float4 hi = *(const float4*)(xp + 4);
                u16x8 px;
                px[0] = f2bu(lo.x); px[1] = f2bu(lo.y); px[2] = f2bu(lo.z); px[3] = f2bu(lo.w);
                px[4] = f2bu(hi.x); px[5] = f2bu(hi.y); px[6] = f2bu(hi.z); px[7] = f2bu(hi.w);
                xf[ks] = __builtin_bit_cast(bf16x8, px);
            }
            floatx4 acc[4];
#pragma unroll
            for (int dt = 0; dt < 4; ++dt) acc[dt] = floatx4{0.f, 0.f, 0.f, 0.f};
            // v transposed: A = Wv rows (d), B = X rows (l) -> C[d][l]
#pragma unroll
            for (int dt = 0; dt < 4; ++dt)
#pragma unroll
                for (int ks = 0; ks < 2; ++ks)
                    acc[dt] = __builtin_amdgcn_mfma_f32_16x16x32_bf16(wf[dt][ks], xf[ks], acc[dt], 0, 0, 0);
            const int bh = bidx * HEADS + h;
#pragma unroll
            for (int dt = 0; dt < 4; ++dt)
#pragma unroll
                for (int i = 0; i < 4; ++i) {
                    const int d = dt * 16 + quad * 4 + i;
                    float val = acc[dt][i] + biasv[dt][i];
                    vtb[((size_t)bh * 64 + d) * SEQ + l0 + l16] = f2bu(val);
                }
        }
    }
}

// ---------------------------------------------------------------------------
// Kernel 2: prep — bf16 conversions with zero padding.
// ---------------------------------------------------------------------------
#define NW (1024 * 1024)
#define NRK (RELK_ROWS * 64)
#define NRV (64 * RELV_STRIDE)
#define NWP (3 * 4096)
__global__ __launch_bounds__(256) void sa_prep_kernel(
    const float* __restrict__ Wfc, const float* __restrict__ relk,
    const float* __restrict__ relv,
    const float* __restrict__ Wq, const float* __restrict__ Wk,
    const float* __restrict__ Wv,
    unsigned short* __restrict__ wfcb, unsigned short* __restrict__ relkb,
    unsigned short* __restrict__ relvtb,
    unsigned short* __restrict__ wqb, unsigned short* __restrict__ wkb,
    unsigned short* __restrict__ wvb) {
    int i = blockIdx.x * 256 + threadIdx.x;
    if (i < NW) {
        wfcb[i] = f2bu(Wfc[i]);
    } else if (i < NW + NRK) {
        int j = i - NW;
        int r = j >> 6, d = j & 63;
        relkb[j] = (r <= 1024) ? f2bu(relk[r * 64 + d]) : 0;
    } else if (i < NW + NRK + NRV) {
        int j = i - NW - NRK;
        int d = j / RELV_STRIDE, c = j - d * RELV_STRIDE;
        relvtb[j] = (c <= 1024) ? f2bu(relv[c * 64 + d]) : 0;
    } else if (i < NW + NRK + NRV + NWP) {
        int j = i - NW - NRK - NRV;
        int which = j >> 12, e = j & 4095;
        const float* src = (which == 0) ? Wq : (which == 1) ? Wk : Wv;
        unsigned short* dst = (which == 0) ? wqb : (which == 1) ? wkb : wvb;
        dst[e] = f2bu(src[e]);
    }
}

// ---------------------------------------------------------------------------
// Kernels 3a/3b: mask all-ones reduction -> flags[b] (no init needed).
// ---------------------------------------------------------------------------
__global__ __launch_bounds__(256) void sa_maskred1(const int* __restrict__ mask,
                                                   unsigned* __restrict__ part) {
    const int b = blockIdx.y, chunk = blockIdx.x;
    const int4* p = (const int4*)(mask + (size_t)b * (SEQ * SEQ) + chunk * 16384);
    int ok = 1;
    const int t = threadIdx.x;
#pragma unroll
    for (int i = 0; i < 16; ++i) {
        int4 v = p[t + i * 256];
        ok &= (v.x != 0 && v.y != 0 && v.z != 0 && v.w != 0) ? 1 : 0;
    }
    unsigned long long bal = __ballot(ok);
    __shared__ unsigned wok[4];
    if ((t & 63) == 0) wok[t >> 6] = (bal == ~0ull) ? 1u : 0u;
    __syncthreads();
    if (t == 0)
        part[b * 64 + chunk] = (wok[0] & wok[1] & wok[2] & wok[3]) ? 0xFFFFFFFFu : 0u;
}
__global__ void sa_maskred2(const unsigned* __restrict__ part, unsigned* __restrict__ flags) {
    int t = threadIdx.x;
    if (t < 4) {
        unsigned f = 0xFFFFFFFFu;
        for (int i = 0; i < 64; ++i) f &= part[t * 64 + i];
        flags[t] = f;
    }
}

// ---------------------------------------------------------------------------
// Kernel 4: MFMA attention. 512 thr (8 waves), 1 block = 16 q rows of (b,h).
// All waves share the 16 rows; wave w owns k-chunk [w*128, w*128+128).
// PbA[row][k]   = p (unshifted)       -> P @ V^T
// PbB[row][c]   = p at c = k-q+512    -> PR @ relv^T (aligned b128 reads;
//                 clip cols c=0/1024 via lowS/highS rank-1 fixups)
// RS (rel scores) overlays PbB (dead before PbB is zero-filled).
// ---------------------------------------------------------------------------
__global__ __launch_bounds__(512, 4) void sa_attn_kernel(
    const unsigned short* __restrict__ qb, const unsigned short* __restrict__ kb,
    const unsigned short* __restrict__ vtb, const int* __restrict__ mask,
    const unsigned short* __restrict__ relkb, const unsigned short* __restrict__ relvtb,
    const unsigned* __restrict__ flags, unsigned short* __restrict__ aob) {
    __shared__ unsigned short PbA[TQ * PBS];
    __shared__ unsigned short PbB[TQ * PBS];
    __shared__ float Ored[TQ * 64];
    __shared__ float wred[4][128];           // [max,sum,low,high][row*8 + wave]
    __shared__ float invS[TQ], lowS[TQ], highS[TQ];

    const int tid = threadIdx.x;
    const int w = tid >> 6, lane = tid & 63;
    const int quad = lane >> 4, l16 = lane & 15;
    const int bid = blockIdx.x;
    const int bh = bid >> 6;
    const int q0 = (bid & 63) * TQ;
    const int b = bh >> 4, h = bh & 15;
    const bool mfull = (flags[b] == 0xFFFFFFFFu);

    // Q A-fragments (all waves: rows q0..q0+15)
    bf16x8 aq[2];
    {
        const unsigned short* qrow = qb + ((size_t)bh * SEQ + q0 + l16) * 64;
        aq[0] = *(const bf16x8*)(qrow + quad * 8);
        aq[1] = *(const bf16x8*)(qrow + 32 + quad * 8);
    }

    // ---- Phase B: RS = Q @ relk^T (overlay in PbB) ----
    unsigned short* RS = PbB;
    for (int rt = w; rt < 65; rt += 8) {
        floatx4 racc = {0.f, 0.f, 0.f, 0.f};
#pragma unroll
        for (int ks = 0; ks < 2; ++ks) {
            bf16x8 bf = *(const bf16x8*)(relkb + (size_t)(rt * 16 + l16) * 64 + ks * 32 + quad * 8);
            racc = __builtin_amdgcn_mfma_f32_16x16x32_bf16(aq[ks], bf, racc, 0, 0, 0);
        }
        const int rcol = rt * 16 + l16;
        if (rcol <= 1024) {
#pragma unroll
            for (int i = 0; i < 4; ++i)
                RS[(quad * 4 + i) * PBS + rcol] = f2bu(racc[i]);
        }
    }
    __syncthreads();

    // ---- Phase C: S = Q@K^T + RS gather (+mask); row max ----
    const int kbase = w * 128;
    floatx4 acc[8];
#pragma unroll
    for (int tt = 0; tt < 8; ++tt) acc[tt] = floatx4{0.f, 0.f, 0.f, 0.f};
#pragma unroll
    for (int tt = 0; tt < 8; ++tt) {
#pragma unroll
        for (int ks = 0; ks < 2; ++ks) {
            bf16x8 bf = *(const bf16x8*)(
                kb + ((size_t)bh * SEQ + kbase + tt * 16 + l16) * 64 + ks * 32 + quad * 8);
            acc[tt] = __builtin_amdgcn_mfma_f32_16x16x32_bf16(aq[ks], bf, acc[tt], 0, 0, 0);
        }
    }
    float rmax[4] = {-3.0e38f, -3.0e38f, -3.0e38f, -3.0e38f};
    if (mfull) {
#pragma unroll
        for (int tt = 0; tt < 8; ++tt) {
            const int k = kbase + tt * 16 + l16;
#pragma unroll
            for (int i = 0; i < 4; ++i) {
                const int row = quad * 4 + i;
                const int q = q0 + row;
                int r = min(512, max(-512, k - q)) + 512;
                float s = acc[tt][i] + b2f(RS[row * PBS + r]);
                acc[tt][i] = s;
                rmax[i] = fmaxf(rmax[i], s);
            }
        }
    } else {
#pragma unroll
        for (int tt = 0; tt < 8; ++tt) {
            const int k = kbase + tt * 16 + l16;
#pragma unroll
            for (int i = 0; i < 4; ++i) {
                const int row = quad * 4 + i;
                const int q = q0 + row;
                int r = min(512, max(-512, k - q)) + 512;
                float s = acc[tt][i] + b2f(RS[row * PBS + r]);
                int m = mask[(size_t)b * (SEQ * SEQ) + (size_t)q * SEQ + k];
                s = (m == 0) ? -1e20f : s;
                acc[tt][i] = s;
                rmax[i] = fmaxf(rmax[i], s);
            }
        }
    }
#pragma unroll
    for (int i = 0; i < 4; ++i) {
#pragma unroll
        for (int o = 1; o < 16; o <<= 1) rmax[i] = fmaxf(rmax[i], __shfl_xor(rmax[i], o));
    }
    if (l16 == 0) {
#pragma unroll
        for (int i = 0; i < 4; ++i) wred[0][(quad * 4 + i) * 8 + w] = rmax[i];
    }
    __syncthreads();

    // ---- zero-fill PbB (RS dead) + read row maxima ----
    for (int g = tid; g < TQ * 129; g += 512) {
        int row = g / 129, s2 = g - row * 129;
        *(uint4*)&PbB[row * PBS + s2 * 8] = make_uint4(0u, 0u, 0u, 0u);
    }
    float mx[4];
#pragma unroll
    for (int i = 0; i < 4; ++i) {
        const int row = quad * 4 + i;
        float4 a = *(float4*)&wred[0][row * 8];
        float4 c = *(float4*)&wred[0][row * 8 + 4];
        mx[i] = fmaxf(fmaxf(fmaxf(a.x, a.y), fmaxf(a.z, a.w)),
                      fmaxf(fmaxf(c.x, c.y), fmaxf(c.z, c.w)));
    }
    __syncthreads();

    // ---- Phase D: exp, sums (+clip tails), dual P store ----
    float ssum[4] = {0.f, 0.f, 0.f, 0.f};
    float slow[4] = {0.f, 0.f, 0.f, 0.f};
    float shigh[4] = {0.f, 0.f, 0.f, 0.f};
#pragma unroll
    for (int tt = 0; tt < 8; ++tt) {
        const int k = kbase + tt * 16 + l16;
#pragma unroll
        for (int i = 0; i < 4; ++i) {
            const int row = quad * 4 + i;
            const int q = q0 + row;
            float p = __expf(acc[tt][i] - mx[i]);
            ssum[i] += p;
            const int dist = k - q;
            slow[i] += (dist <= -512) ? p : 0.f;
            shigh[i] += (dist >= 512) ? p : 0.f;
            unsigned short pv = f2bu(p);
            PbA[row * PBS + k] = pv;
            const int c = dist + 512;
            if ((unsigned)(c - 1) < 1023u) PbB[row * PBS + c] = pv;
        }
    }
#pragma unroll
    for (int i = 0; i < 4; ++i) {
#pragma unroll
        for (int o = 1; o < 16; o <<= 1) {
            ssum[i] += __shfl_xor(ssum[i], o);
            slow[i] += __shfl_xor(slow[i], o);
            shigh[i] += __shfl_xor(shigh[i], o);
        }
    }
    if (l16 == 0) {
#pragma unroll
        for (int i = 0; i < 4; ++i) {
            const int row = quad * 4 + i;
            wred[1][row * 8 + w] = ssum[i];
            wred[2][row * 8 + w] = slow[i];
            wred[3][row * 8 + w] = shigh[i];
        }
    }
    __syncthreads();
    if (tid < TQ) {
        float s = 0.f, lo = 0.f, hi = 0.f;
#pragma unroll
        for (int j = 0; j < 8; ++j) {
            s += wred[1][tid * 8 + j];
            lo += wred[2][tid * 8 + j];
            hi += wred[3][tid * 8 + j];
        }
        invS[tid] = 1.f / s;
        lowS[tid] = lo;
        highS[tid] = hi;
    }
    __syncthreads();

    // ---- Phase F: O = P@V^T + PR@relv^T; split ks across wave pairs ----
    const int d0 = (w & 3) * 16;
    const int khalf = w >> 2;
    floatx4 accA = {0.f, 0.f, 0.f, 0.f};
    floatx4 accB = {0.f, 0.f, 0.f, 0.f};
    const unsigned short* vbase = vtb + ((size_t)bh * 64 + d0 + l16) * SEQ;
    const unsigned short* rbase = relvtb + (size_t)(d0 + l16) * RELV_STRIDE;
    for (int ks = khalf * 16; ks < khalf * 16 + 16; ++ks) {
        const int co = ks * 32 + quad * 8;
        bf16x8 ap = *(const bf16x8*)&PbA[l16 * PBS + co];
        bf16x8 bv = *(const bf16x8*)(vbase + co);
        accA = __builtin_amdgcn_mfma_f32_16x16x32_bf16(ap, bv, accA, 0, 0, 0);
        bf16x8 ar = *(const bf16x8*)&PbB[l16 * PBS + co];
        bf16x8 br = *(const bf16x8*)(rbase + co);
        accB = __builtin_amdgcn_mfma_f32_16x16x32_bf16(ar, br, accB, 0, 0, 0);
    }
    if (w >= 4) {
#pragma unroll
        for (int i = 0; i < 4; ++i)
            Ored[(quad * 4 + i) * 64 + d0 + l16] = accA[i] + accB[i];
    }
    __syncthreads();
    if (w < 4) {
        const float rv0 = b2f(rbase[0]);      // relv[0][d]
        const float rv1 = b2f(rbase[1024]);   // relv[1024][d]
#pragma unroll
        for (int i = 0; i < 4; ++i) {
            const int row = quad * 4 + i;
            float val = accA[i] + accB[i] + Ored[row * 64 + d0 + l16] +
                        lowS[row] * rv0 + highS[row] * rv1;
            val *= invS[row];
            aob[((size_t)(b * SEQ + q0 + row)) * EMB + h * 64 + d0 + l16] = f2bu(val);
        }
    }
}

// ---------------------------------------------------------------------------
// Kernel 5: FC MFMA GEMM. out[4096][1024] = aob @ Wfc_b^T + bfc (fp32 out).
// grid (64, 4); block 256 (4 waves). Block tile M=64, N=256; wave: 32 rows
// (2 m-frags) x 128 cols (8 n-tiles) -> 2x MFMA per W-fragment load.
// ---------------------------------------------------------------------------
__global__ __launch_bounds__(256, 2) void sa_fc_kernel(
    const unsigned short* __restrict__ A, const unsigned short* __restrict__ W,
    const float* __restrict__ bias, float* __restrict__ out) {
    const int t = threadIdx.x;
    const int w = t >> 6, lane = t & 63;
    const int quad = lane >> 4, l16 = lane & 15;
    const int mw = blockIdx.x * 64 + (w & 1) * 32;
    const int nw = blockIdx.y * 256 + (w >> 1) * 128;

    floatx4 acc[2][8];
#pragma unroll
    for (int mt = 0; mt < 2; ++mt)
#pragma unroll
        for (int j = 0; j < 8; ++j) acc[mt][j] = floatx4{0.f, 0.f, 0.f, 0.f};
    float bj[8];
#pragma unroll
    for (int j = 0; j < 8; ++j) bj[j] = bias[nw + j * 16 + l16];

    for (int ks = 0; ks < 32; ++ks) {
        const int co = ks * 32 + quad * 8;
        bf16x8 af0 = *(const bf16x8*)(A + (size_t)(mw + l16) * EMB + co);
        bf16x8 af1 = *(const bf16x8*)(A + (size_t)(mw + 16 + l16) * EMB + co);
#pragma unroll
        for (int j = 0; j < 8; ++j) {
            bf16x8 bf = *(const bf16x8*)(W + (size_t)(nw + j * 16 + l16) * EMB + co);
            acc[0][j] = __builtin_amdgcn_mfma_f32_16x16x32_bf16(af0, bf, acc[0][j], 0, 0, 0);
            acc[1][j] = __builtin_amdgcn_mfma_f32_16x16x32_bf16(af1, bf, acc[1][j], 0, 0, 0);
        }
    }
#pragma unroll
    for (int mt = 0; mt < 2; ++mt)
#pragma unroll
        for (int j = 0; j < 8; ++j) {
            const int col = nw + j * 16 + l16;
#pragma unroll
            for (int i = 0; i < 4; ++i) {
                const size_t row = mw + mt * 16 + quad * 4 + i;
                out[row * EMB + col] = acc[mt][j][i] + bj[j];
            }
        }
}

extern "C" void kernel_launch(void* const* d_in, const int* in_sizes, int n_in,
                              void* d_out, int out_size, void* d_ws, size_t ws_size,
                              hipStream_t stream) {
    const float* query = (const float*)d_in[0];
    const float* key = (const float*)d_in[1];
    const float* value = (const float*)d_in[2];
    const int* mask = (const int*)d_in[3];
    const float* Wq = (const float*)d_in[4];
    const float* bq = (const float*)d_in[5];
    const float* Wk = (const float*)d_in[6];
    const float* bk = (const float*)d_in[7];
    const float* Wv = (const float*)d_in[8];
    const float* bv = (const float*)d_in[9];
    const float* Wfc = (const float*)d_in[10];
    const float* bfc = (const float*)d_in[11];
    const float* relk = (const float*)d_in[12];
    const float* relv = (const float*)d_in[13];
    float* out = (float*)d_out;

    char* base = (char*)d_ws;
    const size_t MB = (size_t)1 << 20;
    unsigned short* qb = (unsigned short*)(base + 0 * MB);
    unsigned short* kb = (unsigned short*)(base + 8 * MB);
    unsigned short* vtb = (unsigned short*)(base + 16 * MB);
    unsigned short* aob = (unsigned short*)(base + 24 * MB);
    unsigned short* wfcb = (unsigned short*)(base + 32 * MB);
    unsigned short* relkb = (unsigned short*)(base + 34 * MB);                 // 133,120 B
    unsigned short* relvtb = (unsigned short*)(base + 34 * MB + 135168);       // 132,096 B
    unsigned short* wqb = (unsigned short*)(base + 34 * MB + 270336);          // 8 KB
    unsigned short* wkb = (unsigned short*)(base + 34 * MB + 278528);
    unsigned short* wvb = (unsigned short*)(base + 34 * MB + 286720);
    unsigned* flags = (unsigned*)(base + 34 * MB + 294912);                    // 16 B
    unsigned* part = (unsigned*)(base + 34 * MB + 295936);                     // 1 KB

    // prep FIRST: proj consumes wqb/wkb/wvb (R3 bug: this order was inverted)
    sa_prep_kernel<<<(NW + NRK + NRV + NWP + 255) / 256, 256, 0, stream>>>(
        Wfc, relk, relv, Wq, Wk, Wv, wfcb, relkb, relvtb, wqb, wkb, wvb);
    sa_proj_kernel<<<dim3(256, 3), 256, 0, stream>>>(
        query, key, value, wqb, wkb, wvb, bq, bk, bv, qb, kb, vtb);
    sa_maskred1<<<dim3(64, 4), 256, 0, stream>>>(mask, part);
    sa_maskred2<<<1, 64, 0, stream>>>(part, flags);
    sa_attn_kernel<<<64 * 64, 512, 0, stream>>>(
        qb, kb, vtb, mask, relkb, relvtb, flags, aob);
    sa_fc_kernel<<<dim3(64, 4), 256, 0, stream>>>(aob, wfcb, bfc, out);
}

// Round 6
// 411.954 us; speedup vs baseline: 2.3583x; 1.0248x over previous
//
#include <hip/hip_runtime.h>
#include <hip/hip_bf16.h>
#include <hip/hip_fp16.h>

#define SEQ 1024
#define HEADS 16
#define HDIM 64
#define EMB 1024
#define TQ 16            // q rows per attention block
#define KH 512           // k per half (split-K)
#define PBA_S 520        // PbA row stride (u16): odd multiple of 8 -> conflict-free b128
#define PBB_S 552        // PbB row stride (u16): odd multiple of 8
#define RELK_ROWS 1040   // 1025 real + zero pad
#define RELV_S 1064      // relv^T padded col stride (zeros past 1024)

typedef __bf16 bf16x8 __attribute__((ext_vector_type(8)));
typedef float floatx4 __attribute__((ext_vector_type(4)));

static __device__ __forceinline__ unsigned short f2bu(float f) {
    __bf16 h = (__bf16)f;                      // native RNE cvt
    return __builtin_bit_cast(unsigned short, h);
}
static __device__ __forceinline__ float b2f(unsigned short u) {
    unsigned v = ((unsigned)u) << 16;
    return __builtin_bit_cast(float, v);
}

// ---------------------------------------------------------------------------
// Kernel 1: MFMA projections (unchanged from R4, which passed).
// ---------------------------------------------------------------------------
__global__ __launch_bounds__(256) void sa_proj_kernel(
    const float* __restrict__ qin, const float* __restrict__ kin,
    const float* __restrict__ vin,
    const unsigned short* __restrict__ wqb, const unsigned short* __restrict__ wkb,
    const unsigned short* __restrict__ wvb,
    const float* __restrict__ bq, const float* __restrict__ bk,
    const float* __restrict__ bv_,
    unsigned short* __restrict__ qb, unsigned short* __restrict__ kb,
    unsigned short* __restrict__ vtb) {
    const int t = threadIdx.x;
    const int w = t >> 6, lane = t & 63;
    const int quad = lane >> 4, l16 = lane & 15;
    const int which = blockIdx.y;
    const int r0 = blockIdx.x * 16;
    const int bidx = r0 >> 10;
    const int l0 = r0 & 1023;
    const float* x = (which == 0) ? qin : (which == 1) ? kin : vin;
    const unsigned short* Wb = (which == 0) ? wqb : (which == 1) ? wkb : wvb;
    const float* bias = (which == 0) ? bq : (which == 1) ? bk : bv_;

    bf16x8 wf[4][2];
#pragma unroll
    for (int dt = 0; dt < 4; ++dt)
#pragma unroll
        for (int ks = 0; ks < 2; ++ks)
            wf[dt][ks] = *(const bf16x8*)(Wb + (size_t)(dt * 16 + l16) * 64 + ks * 32 + quad * 8);

    if (which < 2) {
        float biasd[4];
#pragma unroll
        for (int dt = 0; dt < 4; ++dt) biasd[dt] = bias[dt * 16 + l16];
        const float sc = (which == 0) ? 0.125f : 1.0f;
        unsigned short* dst = (which == 0) ? qb : kb;
        for (int hh = 0; hh < 4; ++hh) {
            const int h = w * 4 + hh;
            bf16x8 xf[2];
#pragma unroll
            for (int ks = 0; ks < 2; ++ks) {
                const float* xp = x + (size_t)(r0 + l16) * EMB + h * 64 + ks * 32 + quad * 8;
                float4 lo = *(const float4*)xp;
                float4 hi = *(const float4*)(xp + 4);
                unsigned short px[8];
                px[0] = f2bu(lo.x); px[1] = f2bu(lo.y); px[2] = f2bu(lo.z); px[3] = f2bu(lo.w);
                px[4] = f2bu(hi.x); px[5] = f2bu(hi.y); px[6] = f2bu(hi.z); px[7] = f2bu(hi.w);
                xf[ks] = *(bf16x8*)px;
            }
            floatx4 acc[4];
#pragma unroll
            for (int dt = 0; dt < 4; ++dt) acc[dt] = floatx4{0.f, 0.f, 0.f, 0.f};
#pragma unroll
            for (int dt = 0; dt < 4; ++dt)
#pragma unroll
                for (int ks = 0; ks < 2; ++ks)
                    acc[dt] = __builtin_amdgcn_mfma_f32_16x16x32_bf16(xf[ks], wf[dt][ks], acc[dt], 0, 0, 0);
            const int bh = bidx * HEADS + h;
#pragma unroll
            for (int dt = 0; dt < 4; ++dt)
#pragma unroll
                for (int i = 0; i < 4; ++i) {
                    const int lr = l0 + quad * 4 + i;
                    float val = (acc[dt][i] + biasd[dt]) * sc;
                    dst[((size_t)bh * SEQ + lr) * 64 + dt * 16 + l16] = f2bu(val);
                }
        }
    } else {
        float biasv[4][4];
#pragma unroll
        for (int dt = 0; dt < 4; ++dt)
#pragma unroll
            for (int i = 0; i < 4; ++i) biasv[dt][i] = bias[dt * 16 + quad * 4 + i];
        for (int hh = 0; hh < 4; ++hh) {
            const int h = w * 4 + hh;
            bf16x8 xf[2];
#pragma unroll
            for (int ks = 0; ks < 2; ++ks) {
                const float* xp = x + (size_t)(r0 + l16) * EMB + h * 64 + ks * 32 + quad * 8;
                float4 lo = *(const float4*)xp;
                float4 hi = *(const float4*)(xp + 4);
                unsigned short px[8];
                px[0] = f2bu(lo.x); px[1] = f2bu(lo.y); px[2] = f2bu(lo.z); px[3] = f2bu(lo.w);
                px[4] = f2bu(hi.x); px[5] = f2bu(hi.y); px[6] = f2bu(hi.z); px[7] = f2bu(hi.w);
                xf[ks] = *(bf16x8*)px;
            }
            floatx4 acc[4];
#pragma unroll
            for (int dt = 0; dt < 4; ++dt) acc[dt] = floatx4{0.f, 0.f, 0.f, 0.f};
#pragma unroll
            for (int dt = 0; dt < 4; ++dt)
#pragma unroll
                for (int ks = 0; ks < 2; ++ks)
                    acc[dt] = __builtin_amdgcn_mfma_f32_16x16x32_bf16(wf[dt][ks], xf[ks], acc[dt], 0, 0, 0);
            const int bh = bidx * HEADS + h;
#pragma unroll
            for (int dt = 0; dt < 4; ++dt)
#pragma unroll
                for (int i = 0; i < 4; ++i) {
                    const int d = dt * 16 + quad * 4 + i;
                    float val = acc[dt][i] + biasv[dt][i];
                    vtb[((size_t)bh * 64 + d) * SEQ + l0 + l16] = f2bu(val);
                }
        }
    }
}

// ---------------------------------------------------------------------------
// Kernel 2: prep (bf16 conversions/padding) + mask all-ones partial reduction.
// ---------------------------------------------------------------------------
#define NW (1024 * 1024)
#define NRK (RELK_ROWS * 64)
#define NRV (64 * RELV_S)
#define NWP (3 * 4096)
#define CONV_BLOCKS ((NW + NRK + NRV + NWP) / 256)   // = 4670 exactly
__global__ __launch_bounds__(256) void sa_prep_kernel(
    const float* __restrict__ Wfc, const float* __restrict__ relk,
    const float* __restrict__ relv,
    const float* __restrict__ Wq, const float* __restrict__ Wk,
    const float* __restrict__ Wv, const int* __restrict__ mask,
    unsigned short* __restrict__ wfcb, unsigned short* __restrict__ relkb,
    unsigned short* __restrict__ relvtb,
    unsigned short* __restrict__ wqb, unsigned short* __restrict__ wkb,
    unsigned short* __restrict__ wvb, unsigned* __restrict__ part) {
    const int bx = blockIdx.x;
    const int t = threadIdx.x;
    if (bx < CONV_BLOCKS) {
        int i = bx * 256 + t;
        if (i < NW) {
            wfcb[i] = f2bu(Wfc[i]);
        } else if (i < NW + NRK) {
            int j = i - NW;
            int r = j >> 6, d = j & 63;
            relkb[j] = (r <= 1024) ? f2bu(relk[r * 64 + d]) : 0;
        } else if (i < NW + NRK + NRV) {
            int j = i - NW - NRK;
            int d = j / RELV_S, c = j - d * RELV_S;
            relvtb[j] = (c <= 1024) ? f2bu(relv[c * 64 + d]) : 0;
        } else {
            int j = i - NW - NRK - NRV;
            int which = j >> 12, e = j & 4095;
            const float* src = (which == 0) ? Wq : (which == 1) ? Wk : Wv;
            unsigned short* dst = (which == 0) ? wqb : (which == 1) ? wkb : wvb;
            dst[e] = f2bu(src[e]);
        }
    } else {
        const int mb = bx - CONV_BLOCKS;
        const int b = mb >> 6, chunk = mb & 63;
        const int4* p = (const int4*)(mask + (size_t)b * (SEQ * SEQ) + chunk * 16384);
        int ok = 1;
#pragma unroll
        for (int i = 0; i < 16; ++i) {
            int4 v = p[t + i * 256];
            ok &= (v.x != 0 && v.y != 0 && v.z != 0 && v.w != 0) ? 1 : 0;
        }
        unsigned long long bal = __ballot(ok);
        __shared__ unsigned wok[4];
        if ((t & 63) == 0) wok[t >> 6] = (bal == ~0ull) ? 1u : 0u;
        __syncthreads();
        if (t == 0)
            part[b * 64 + chunk] = (wok[0] & wok[1] & wok[2] & wok[3]) ? 0xFFFFFFFFu : 0u;
    }
}

__global__ void sa_maskred2(const unsigned* __restrict__ part, unsigned* __restrict__ flags) {
    int t = threadIdx.x;
    if (t < 4) {
        unsigned f = 0xFFFFFFFFu;
        for (int i = 0; i < 64; ++i) f &= part[t * 64 + i];
        flags[t] = f;
    }
}

// ---------------------------------------------------------------------------
// Kernel 3: split-K MFMA attention (R5 design; FIX: clip-tail rank-1 fixup
// applied exactly once, in the w<4 epilogue — R5 applied it in all 8 waves,
// double-counting it through the Ored reduction -> absmax 0.04).
// ---------------------------------------------------------------------------
__global__ __launch_bounds__(512, 8) void sa_attn_kernel(
    const unsigned short* __restrict__ qb, const unsigned short* __restrict__ kb,
    const unsigned short* __restrict__ vtb, const int* __restrict__ mask,
    const unsigned short* __restrict__ relkb, const unsigned short* __restrict__ relvtb,
    const unsigned* __restrict__ flags, __half* __restrict__ Opart,
    float2* __restrict__ ms) {
    __shared__ __align__(16) unsigned short PbA[TQ * PBA_S];  // p by local k
    __shared__ __align__(16) unsigned short PbB[TQ * PBB_S];  // RS, then shifted p
    __shared__ float Ored[TQ * 64];
    __shared__ float wred[4][128];     // [max,sum,low,high][row*8 + wave]
    __shared__ float lowS[TQ], highS[TQ];

    const int tid = threadIdx.x;
    const int w = tid >> 6, lane = tid & 63;
    const int quad = lane >> 4, l16 = lane & 15;
    const int bid = blockIdx.x;
    const int hf = bid & 1;
    const int qt = (bid >> 1) & 63;
    const int bh = bid >> 7;
    const int q0 = qt * TQ;
    const int k0 = hf * KH;
    const int b = bh >> 4;
    const bool mfull = (flags[b] == 0xFFFFFFFFu);

    // c-window of this (q-tile, k-half): c = clip(k-q,±512)+512
    const int cmin = min(512, max(-512, k0 - (q0 + 15))) + 512;
    const int cmax = min(512, max(-512, k0 + 511 - q0)) + 512;
    const int rsb = cmin & ~15;   // RS storage base (16-tile aligned)
    const int cb0 = cmin & ~7;    // PbB storage base (16B aligned)

    // Q A-fragments (rows q0..q0+15)
    bf16x8 aq[2];
    {
        const unsigned short* qrow = qb + ((size_t)bh * SEQ + q0 + l16) * 64;
        aq[0] = *(const bf16x8*)(qrow + quad * 8);
        aq[1] = *(const bf16x8*)(qrow + 32 + quad * 8);
    }

    // ---- Phase B: RS = Q @ relk^T over the window (overlay in PbB) ----
    {
        const int rt_lo = cmin >> 4, rt_hi = cmax >> 4;
        for (int rt = rt_lo + w; rt <= rt_hi; rt += 8) {
            floatx4 racc = {0.f, 0.f, 0.f, 0.f};
#pragma unroll
            for (int ks = 0; ks < 2; ++ks) {
                bf16x8 bf = *(const bf16x8*)(relkb + (size_t)(rt * 16 + l16) * 64 + ks * 32 + quad * 8);
                racc = __builtin_amdgcn_mfma_f32_16x16x32_bf16(aq[ks], bf, racc, 0, 0, 0);
            }
            const int rcol = rt * 16 + l16;
            if (rcol <= cmax) {
#pragma unroll
                for (int i = 0; i < 4; ++i)
                    PbB[(quad * 4 + i) * PBB_S + (rcol - rsb)] = f2bu(racc[i]);
            }
        }
    }
    __syncthreads();

    // ---- Phase C: S = Q@K^T + RS gather (+mask); row max ----
    const int kbase = k0 + w * 64;
    floatx4 acc[4];
#pragma unroll
    for (int tt = 0; tt < 4; ++tt) acc[tt] = floatx4{0.f, 0.f, 0.f, 0.f};
#pragma unroll
    for (int tt = 0; tt < 4; ++tt) {
#pragma unroll
        for (int ks = 0; ks < 2; ++ks) {
            bf16x8 bf = *(const bf16x8*)(
                kb + ((size_t)bh * SEQ + kbase + tt * 16 + l16) * 64 + ks * 32 + quad * 8);
            acc[tt] = __builtin_amdgcn_mfma_f32_16x16x32_bf16(aq[ks], bf, acc[tt], 0, 0, 0);
        }
    }
    float rmax[4] = {-3.0e38f, -3.0e38f, -3.0e38f, -3.0e38f};
    if (mfull) {
#pragma unroll
        for (int tt = 0; tt < 4; ++tt) {
            const int k = kbase + tt * 16 + l16;
#pragma unroll
            for (int i = 0; i < 4; ++i) {
                const int row = quad * 4 + i;
                const int q = q0 + row;
                int r = min(512, max(-512, k - q)) + 512;
                float s = acc[tt][i] + b2f(PbB[row * PBB_S + (r - rsb)]);
                acc[tt][i] = s;
                rmax[i] = fmaxf(rmax[i], s);
            }
        }
    } else {
#pragma unroll
        for (int tt = 0; tt < 4; ++tt) {
            const int k = kbase + tt * 16 + l16;
#pragma unroll
            for (int i = 0; i < 4; ++i) {
                const int row = quad * 4 + i;
                const int q = q0 + row;
                int r = min(512, max(-512, k - q)) + 512;
                float s = acc[tt][i] + b2f(PbB[row * PBB_S + (r - rsb)]);
                int m = mask[(size_t)b * (SEQ * SEQ) + (size_t)q * SEQ + k];
                s = (m == 0) ? -1e20f : s;
                acc[tt][i] = s;
                rmax[i] = fmaxf(rmax[i], s);
            }
        }
    }
#pragma unroll
    for (int i = 0; i < 4; ++i) {
#pragma unroll
        for (int o = 1; o < 16; o <<= 1) rmax[i] = fmaxf(rmax[i], __shfl_xor(rmax[i], o));
    }
    if (l16 == 0) {
#pragma unroll
        for (int i = 0; i < 4; ++i) wred[0][(quad * 4 + i) * 8 + w] = rmax[i];
    }
    __syncthreads();

    // ---- zero-fill PbB (RS dead) + per-lane row maxima ----
    for (int g = tid; g < TQ * (PBB_S / 8); g += 512) {
        int row = g / (PBB_S / 8), j = g - row * (PBB_S / 8);
        *(uint4*)&PbB[row * PBB_S + j * 8] = make_uint4(0u, 0u, 0u, 0u);
    }
    float mx[4];
#pragma unroll
    for (int i = 0; i < 4; ++i) {
        const int row = quad * 4 + i;
        float4 a = *(float4*)&wred[0][row * 8];
        float4 c = *(float4*)&wred[0][row * 8 + 4];
        mx[i] = fmaxf(fmaxf(fmaxf(a.x, a.y), fmaxf(a.z, a.w)),
                      fmaxf(fmaxf(c.x, c.y), fmaxf(c.z, c.w)));
    }
    __syncthreads();

    // ---- Phase D: exp, sums (+clip tails), dual P store ----
    float ssum[4] = {0.f, 0.f, 0.f, 0.f};
    float slow[4] = {0.f, 0.f, 0.f, 0.f};
    float shigh[4] = {0.f, 0.f, 0.f, 0.f};
#pragma unroll
    for (int tt = 0; tt < 4; ++tt) {
        const int k = kbase + tt * 16 + l16;
#pragma unroll
        for (int i = 0; i < 4; ++i) {
            const int row = quad * 4 + i;
            const int q = q0 + row;
            float p = __expf(acc[tt][i] - mx[i]);
            ssum[i] += p;
            const int dist = k - q;
            slow[i] += (dist <= -512) ? p : 0.f;
            shigh[i] += (dist >= 512) ? p : 0.f;
            unsigned short pv = f2bu(p);
            PbA[row * PBA_S + (k - k0)] = pv;
            const int c = dist + 512;
            if ((unsigned)(c - 1) < 1023u) PbB[row * PBB_S + (c - cb0)] = pv;
        }
    }
#pragma unroll
    for (int i = 0; i < 4; ++i) {
#pragma unroll
        for (int o = 1; o < 16; o <<= 1) {
            ssum[i] += __shfl_xor(ssum[i], o);
            slow[i] += __shfl_xor(slow[i], o);
            shigh[i] += __shfl_xor(shigh[i], o);
        }
    }
    if (l16 == 0) {
#pragma unroll
        for (int i = 0; i < 4; ++i) {
            const int row = quad * 4 + i;
            wred[1][row * 8 + w] = ssum[i];
            wred[2][row * 8 + w] = slow[i];
            wred[3][row * 8 + w] = shigh[i];
        }
    }
    __syncthreads();
    if (tid < TQ) {
        float m = wred[0][tid * 8];
        float s = 0.f, lo = 0.f, hi = 0.f;
#pragma unroll
        for (int j = 0; j < 8; ++j) {
            m = fmaxf(m, wred[0][tid * 8 + j]);
            s += wred[1][tid * 8 + j];
            lo += wred[2][tid * 8 + j];
            hi += wred[3][tid * 8 + j];
        }
        lowS[tid] = lo;
        highS[tid] = hi;
        const int R = bh * SEQ + q0 + tid;
        ms[(size_t)R * 2 + hf] = make_float2(m, s);
    }
    __syncthreads();

    // ---- Phase F: O_half = P@V^T + PR@relv^T; clip fixup ONCE in epilogue ----
    const int d0 = (w & 3) * 16;
    const int kg = w >> 2;
    floatx4 accA = {0.f, 0.f, 0.f, 0.f};
    floatx4 accB = {0.f, 0.f, 0.f, 0.f};
    const unsigned short* vbase = vtb + ((size_t)bh * 64 + d0 + l16) * SEQ + k0;
    const unsigned short* rbase = relvtb + (size_t)(d0 + l16) * RELV_S;
    for (int ks = kg; ks < 16; ks += 2) {
        const int co = ks * 32 + quad * 8;
        bf16x8 ap = *(const bf16x8*)&PbA[l16 * PBA_S + co];
        bf16x8 bv = *(const bf16x8*)(vbase + co);
        accA = __builtin_amdgcn_mfma_f32_16x16x32_bf16(ap, bv, accA, 0, 0, 0);
    }
    const int nksB = ((cmax - cb0) >> 5) + 1;
    for (int ks = kg; ks < nksB; ks += 2) {
        const int co = ks * 32 + quad * 8;
        bf16x8 ar = *(const bf16x8*)&PbB[l16 * PBB_S + co];
        bf16x8 br = *(const bf16x8*)(rbase + cb0 + co);
        accB = __builtin_amdgcn_mfma_f32_16x16x32_bf16(ar, br, accB, 0, 0, 0);
    }
    if (w >= 4) {
#pragma unroll
        for (int i = 0; i < 4; ++i)
            Ored[(quad * 4 + i) * 64 + d0 + l16] = accA[i] + accB[i];
    }
    __syncthreads();
    if (w < 4) {
        const float rv0 = b2f(rbase[0]);      // relv[0][d]    (low-clip column)
        const float rv1 = b2f(rbase[1024]);   // relv[1024][d] (high-clip column)
#pragma unroll
        for (int i = 0; i < 4; ++i) {
            const int row = quad * 4 + i;
            const int R = bh * SEQ + q0 + row;
            float val = accA[i] + accB[i] + Ored[row * 64 + d0 + l16] +
                        lowS[row] * rv0 + highS[row] * rv1;
            Opart[((size_t)R * 2 + hf) * 64 + d0 + l16] = __float2half(val);
        }
    }
}

// ---------------------------------------------------------------------------
// Kernel 4: combine the two k-halves (flash-style rescale) -> aob bf16.
// ---------------------------------------------------------------------------
__global__ __launch_bounds__(256) void sa_combine_kernel(
    const __half* __restrict__ Opart, const float2* __restrict__ ms,
    unsigned short* __restrict__ aob) {
    const int tid = threadIdx.x;
    const int R = blockIdx.x * 4 + (tid >> 6);
    const int d = tid & 63;
    float2 s0 = ms[(size_t)R * 2 + 0];
    float2 s1 = ms[(size_t)R * 2 + 1];
    float m = fmaxf(s0.x, s1.x);
    float a0 = __expf(s0.x - m), a1 = __expf(s1.x - m);
    float inv = 1.f / (s0.y * a0 + s1.y * a1);
    float O0 = __half2float(Opart[((size_t)R * 2 + 0) * 64 + d]);
    float O1 = __half2float(Opart[((size_t)R * 2 + 1) * 64 + d]);
    float val = (O0 * a0 + O1 * a1) * inv;
    const int bh = R >> 10, q = R & 1023, b = bh >> 4, h = bh & 15;
    aob[((size_t)b * SEQ + q) * EMB + h * 64 + d] = f2bu(val);
}

// ---------------------------------------------------------------------------
// Kernel 5: FC MFMA GEMM (unchanged from R4). out = aob @ Wfc_b^T + bfc.
// ---------------------------------------------------------------------------
__global__ __launch_bounds__(256, 2) void sa_fc_kernel(
    const unsigned short* __restrict__ A, const unsigned short* __restrict__ W,
    const float* __restrict__ bias, float* __restrict__ out) {
    const int t = threadIdx.x;
    const int w = t >> 6, lane = t & 63;
    const int quad = lane >> 4, l16 = lane & 15;
    const int mw = blockIdx.x * 64 + (w & 1) * 32;
    const int nw = blockIdx.y * 256 + (w >> 1) * 128;

    floatx4 acc[2][8];
#pragma unroll
    for (int mt = 0; mt < 2; ++mt)
#pragma unroll
        for (int j = 0; j < 8; ++j) acc[mt][j] = floatx4{0.f, 0.f, 0.f, 0.f};
    float bj[8];
#pragma unroll
    for (int j = 0; j < 8; ++j) bj[j] = bias[nw + j * 16 + l16];

    for (int ks = 0; ks < 32; ++ks) {
        const int co = ks * 32 + quad * 8;
        bf16x8 af0 = *(const bf16x8*)(A + (size_t)(mw + l16) * EMB + co);
        bf16x8 af1 = *(const bf16x8*)(A + (size_t)(mw + 16 + l16) * EMB + co);
#pragma unroll
        for (int j = 0; j < 8; ++j) {
            bf16x8 bf = *(const bf16x8*)(W + (size_t)(nw + j * 16 + l16) * EMB + co);
            acc[0][j] = __builtin_amdgcn_mfma_f32_16x16x32_bf16(af0, bf, acc[0][j], 0, 0, 0);
            acc[1][j] = __builtin_amdgcn_mfma_f32_16x16x32_bf16(af1, bf, acc[1][j], 0, 0, 0);
        }
    }
#pragma unroll
    for (int mt = 0; mt < 2; ++mt)
#pragma unroll
        for (int j = 0; j < 8; ++j) {
            const int col = nw + j * 16 + l16;
#pragma unroll
            for (int i = 0; i < 4; ++i) {
                const size_t row = mw + mt * 16 + quad * 4 + i;
                out[row * EMB + col] = acc[mt][j][i] + bj[j];
            }
        }
}

extern "C" void kernel_launch(void* const* d_in, const int* in_sizes, int n_in,
                              void* d_out, int out_size, void* d_ws, size_t ws_size,
                              hipStream_t stream) {
    const float* query = (const float*)d_in[0];
    const float* key = (const float*)d_in[1];
    const float* value = (const float*)d_in[2];
    const int* mask = (const int*)d_in[3];
    const float* Wq = (const float*)d_in[4];
    const float* bq = (const float*)d_in[5];
    const float* Wk = (const float*)d_in[6];
    const float* bk = (const float*)d_in[7];
    const float* Wv = (const float*)d_in[8];
    const float* bv = (const float*)d_in[9];
    const float* Wfc = (const float*)d_in[10];
    const float* bfc = (const float*)d_in[11];
    const float* relk = (const float*)d_in[12];
    const float* relv = (const float*)d_in[13];
    float* out = (float*)d_out;

    char* base = (char*)d_ws;
    const size_t MB = (size_t)1 << 20;
    unsigned short* qb = (unsigned short*)(base + 0 * MB);
    unsigned short* kb = (unsigned short*)(base + 8 * MB);
    unsigned short* vtb = (unsigned short*)(base + 16 * MB);
    unsigned short* aob = (unsigned short*)(base + 24 * MB);
    unsigned short* wfcb = (unsigned short*)(base + 32 * MB);
    unsigned short* relkb = (unsigned short*)(base + 34 * MB);                // 133,120 B
    unsigned short* relvtb = (unsigned short*)(base + 34 * MB + 262144);      // 136,192 B
    unsigned short* wqb = (unsigned short*)(base + 34 * MB + 524288);         // 8 KB each
    unsigned short* wkb = (unsigned short*)(base + 34 * MB + 532480);
    unsigned short* wvb = (unsigned short*)(base + 34 * MB + 540672);
    unsigned* flags = (unsigned*)(base + 34 * MB + 548864);                   // 16 B
    unsigned* part = (unsigned*)(base + 34 * MB + 552960);                    // 1 KB
    float2* ms = (float2*)(base + 35 * MB);                                   // 1 MB
    __half* Opart = (__half*)(base + 36 * MB);                                // 16 MB

    // prep FIRST: proj consumes bf16 weights; attn consumes rel tables+flags.
    sa_prep_kernel<<<CONV_BLOCKS + 256, 256, 0, stream>>>(
        Wfc, relk, relv, Wq, Wk, Wv, mask, wfcb, relkb, relvtb, wqb, wkb, wvb, part);
    sa_proj_kernel<<<dim3(256, 3), 256, 0, stream>>>(
        query, key, value, wqb, wkb, wvb, bq, bk, bv, qb, kb, vtb);
    sa_maskred2<<<1, 64, 0, stream>>>(part, flags);
    sa_attn_kernel<<<64 * 64 * 2, 512, 0, stream>>>(
        qb, kb, vtb, mask, relkb, relvtb, flags, Opart, ms);
    sa_combine_kernel<<<(4 * HEADS * SEQ) / 4, 256, 0, stream>>>(Opart, ms, aob);
    sa_fc_kernel<<<dim3(64, 4), 256, 0, stream>>>(aob, wfcb, bfc, out);
}

// Round 7
// 402.247 us; speedup vs baseline: 2.4152x; 1.0241x over previous
//
#include <hip/hip_runtime.h>
#include <hip/hip_bf16.h>
#include <hip/hip_fp16.h>

#define SEQ 1024
#define HEADS 16
#define HDIM 64
#define EMB 1024
#define TQ 32            // q rows per attention block (2 row-tiles)
#define KQ 256           // k per quarter (split-K/4)
#define PBA_S 264        // PbA row stride (u16): 256+8, odd mult of 8
#define PBB_S 328        // PbB row stride (u16): window<=295 + read slack -> 328
#define RELK_ROWS 1040   // 1025 real + zero pad
#define RELV_S 1064      // relv^T padded col stride (zeros past 1024)

typedef __bf16 bf16x8 __attribute__((ext_vector_type(8)));
typedef float floatx4 __attribute__((ext_vector_type(4)));

static __device__ __forceinline__ unsigned short f2bu(float f) {
    __bf16 h = (__bf16)f;
    return __builtin_bit_cast(unsigned short, h);
}
static __device__ __forceinline__ float b2f(unsigned short u) {
    unsigned v = ((unsigned)u) << 16;
    return __builtin_bit_cast(float, v);
}

// ---------------------------------------------------------------------------
// Kernel 1: MFMA projections. grid (1024, 3): bx>>2 -> 16-row tile, bx&3 ->
// head group; each wave handles ONE head (4x more blocks than R6 for latency
// hiding). Depends on sa_prep_kernel (bf16 weights) having run FIRST.
// ---------------------------------------------------------------------------
__global__ __launch_bounds__(256) void sa_proj_kernel(
    const float* __restrict__ qin, const float* __restrict__ kin,
    const float* __restrict__ vin,
    const unsigned short* __restrict__ wqb, const unsigned short* __restrict__ wkb,
    const unsigned short* __restrict__ wvb,
    const float* __restrict__ bq, const float* __restrict__ bk,
    const float* __restrict__ bv_,
    unsigned short* __restrict__ qb, unsigned short* __restrict__ kb,
    unsigned short* __restrict__ vtb) {
    const int t = threadIdx.x;
    const int w = t >> 6, lane = t & 63;
    const int quad = lane >> 4, l16 = lane & 15;
    const int which = blockIdx.y;
    const int bx = blockIdx.x;
    const int r0 = (bx >> 2) * 16;
    const int h = (bx & 3) * 4 + w;
    const int bidx = r0 >> 10;
    const int l0 = r0 & 1023;
    const float* x = (which == 0) ? qin : (which == 1) ? kin : vin;
    const unsigned short* Wb = (which == 0) ? wqb : (which == 1) ? wkb : wvb;
    const float* bias = (which == 0) ? bq : (which == 1) ? bk : bv_;

    bf16x8 wf[4][2];
#pragma unroll
    for (int dt = 0; dt < 4; ++dt)
#pragma unroll
        for (int ks = 0; ks < 2; ++ks)
            wf[dt][ks] = *(const bf16x8*)(Wb + (size_t)(dt * 16 + l16) * 64 + ks * 32 + quad * 8);

    bf16x8 xf[2];
#pragma unroll
    for (int ks = 0; ks < 2; ++ks) {
        const float* xp = x + (size_t)(r0 + l16) * EMB + h * 64 + ks * 32 + quad * 8;
        float4 lo = *(const float4*)xp;
        float4 hi = *(const float4*)(xp + 4);
        unsigned short px[8];
        px[0] = f2bu(lo.x); px[1] = f2bu(lo.y); px[2] = f2bu(lo.z); px[3] = f2bu(lo.w);
        px[4] = f2bu(hi.x); px[5] = f2bu(hi.y); px[6] = f2bu(hi.z); px[7] = f2bu(hi.w);
        xf[ks] = *(bf16x8*)px;
    }
    const int bh = bidx * HEADS + h;

    if (which < 2) {
        float biasd[4];
#pragma unroll
        for (int dt = 0; dt < 4; ++dt) biasd[dt] = bias[dt * 16 + l16];
        const float sc = (which == 0) ? 0.125f : 1.0f;
        unsigned short* dst = (which == 0) ? qb : kb;
        floatx4 acc[4];
#pragma unroll
        for (int dt = 0; dt < 4; ++dt) acc[dt] = floatx4{0.f, 0.f, 0.f, 0.f};
#pragma unroll
        for (int dt = 0; dt < 4; ++dt)
#pragma unroll
            for (int ks = 0; ks < 2; ++ks)
                acc[dt] = __builtin_amdgcn_mfma_f32_16x16x32_bf16(xf[ks], wf[dt][ks], acc[dt], 0, 0, 0);
#pragma unroll
        for (int dt = 0; dt < 4; ++dt)
#pragma unroll
            for (int i = 0; i < 4; ++i) {
                const int lr = l0 + quad * 4 + i;
                float val = (acc[dt][i] + biasd[dt]) * sc;
                dst[((size_t)bh * SEQ + lr) * 64 + dt * 16 + l16] = f2bu(val);
            }
    } else {
        float biasv[4][4];
#pragma unroll
        for (int dt = 0; dt < 4; ++dt)
#pragma unroll
            for (int i = 0; i < 4; ++i) biasv[dt][i] = bias[dt * 16 + quad * 4 + i];
        floatx4 acc[4];
#pragma unroll
        for (int dt = 0; dt < 4; ++dt) acc[dt] = floatx4{0.f, 0.f, 0.f, 0.f};
        // v transposed: A = Wv rows (d), B = X rows (l) -> C[d][l]
#pragma unroll
        for (int dt = 0; dt < 4; ++dt)
#pragma unroll
            for (int ks = 0; ks < 2; ++ks)
                acc[dt] = __builtin_amdgcn_mfma_f32_16x16x32_bf16(wf[dt][ks], xf[ks], acc[dt], 0, 0, 0);
#pragma unroll
        for (int dt = 0; dt < 4; ++dt)
#pragma unroll
            for (int i = 0; i < 4; ++i) {
                const int d = dt * 16 + quad * 4 + i;
                float val = acc[dt][i] + biasv[dt][i];
                vtb[((size_t)bh * 64 + d) * SEQ + l0 + l16] = f2bu(val);
            }
    }
}

// ---------------------------------------------------------------------------
// Kernel 2: prep (bf16 conversions/padding) + mask all-ones partial reduction.
// ---------------------------------------------------------------------------
#define NW (1024 * 1024)
#define NRK (RELK_ROWS * 64)
#define NRV (64 * RELV_S)
#define NWP (3 * 4096)
#define CONV_BLOCKS ((NW + NRK + NRV + NWP) / 256)   // = 4670 exactly
__global__ __launch_bounds__(256) void sa_prep_kernel(
    const float* __restrict__ Wfc, const float* __restrict__ relk,
    const float* __restrict__ relv,
    const float* __restrict__ Wq, const float* __restrict__ Wk,
    const float* __restrict__ Wv, const int* __restrict__ mask,
    unsigned short* __restrict__ wfcb, unsigned short* __restrict__ relkb,
    unsigned short* __restrict__ relvtb,
    unsigned short* __restrict__ wqb, unsigned short* __restrict__ wkb,
    unsigned short* __restrict__ wvb, unsigned* __restrict__ part) {
    const int bx = blockIdx.x;
    const int t = threadIdx.x;
    if (bx < CONV_BLOCKS) {
        int i = bx * 256 + t;
        if (i < NW) {
            wfcb[i] = f2bu(Wfc[i]);
        } else if (i < NW + NRK) {
            int j = i - NW;
            int r = j >> 6, d = j & 63;
            relkb[j] = (r <= 1024) ? f2bu(relk[r * 64 + d]) : 0;
        } else if (i < NW + NRK + NRV) {
            int j = i - NW - NRK;
            int d = j / RELV_S, c = j - d * RELV_S;
            relvtb[j] = (c <= 1024) ? f2bu(relv[c * 64 + d]) : 0;
        } else {
            int j = i - NW - NRK - NRV;
            int which = j >> 12, e = j & 4095;
            const float* src = (which == 0) ? Wq : (which == 1) ? Wk : Wv;
            unsigned short* dst = (which == 0) ? wqb : (which == 1) ? wkb : wvb;
            dst[e] = f2bu(src[e]);
        }
    } else {
        const int mb = bx - CONV_BLOCKS;
        const int b = mb >> 6, chunk = mb & 63;
        const int4* p = (const int4*)(mask + (size_t)b * (SEQ * SEQ) + chunk * 16384);
        int ok = 1;
#pragma unroll
        for (int i = 0; i < 16; ++i) {
            int4 v = p[t + i * 256];
            ok &= (v.x != 0 && v.y != 0 && v.z != 0 && v.w != 0) ? 1 : 0;
        }
        unsigned long long bal = __ballot(ok);
        __shared__ unsigned wok[4];
        if ((t & 63) == 0) wok[t >> 6] = (bal == ~0ull) ? 1u : 0u;
        __syncthreads();
        if (t == 0)
            part[b * 64 + chunk] = (wok[0] & wok[1] & wok[2] & wok[3]) ? 0xFFFFFFFFu : 0u;
    }
}

__global__ void sa_maskred2(const unsigned* __restrict__ part, unsigned* __restrict__ flags) {
    int t = threadIdx.x;
    if (t < 4) {
        unsigned f = 0xFFFFFFFFu;
        for (int i = 0; i < 64; ++i) f &= part[t * 64 + i];
        flags[t] = f;
    }
}

// ---------------------------------------------------------------------------
// Kernel 3: quarter-K MFMA attention. 8192 blocks (bh x 32 qtiles x 4
// quarters), 512 thr (8 waves). Block = 32 q rows x 256 k. Every B-fragment
// (K/relk/V/relv) is loaded once and MFMA'd against BOTH row-tiles (register
// reuse). LDS exactly 40960 B -> 4 blocks/CU. One tail sum per row (a 256-wide
// k-window can never clip both sides); stats overlay wred[0] slots.
// ---------------------------------------------------------------------------
__global__ __launch_bounds__(512, 8) void sa_attn_kernel(
    const unsigned short* __restrict__ qb, const unsigned short* __restrict__ kb,
    const unsigned short* __restrict__ vtb, const int* __restrict__ mask,
    const unsigned short* __restrict__ relkb, const unsigned short* __restrict__ relvtb,
    const unsigned* __restrict__ flags, __half* __restrict__ Opart,
    float2* __restrict__ ms) {
    __shared__ __align__(16) unsigned short PbA[TQ * PBA_S];  // 16896 B
    __shared__ __align__(16) unsigned short PbB[TQ * PBB_S];  // 20992 B (RS overlay)
    __shared__ float wred[3][TQ * 8];                         // 3072 B
    // wred[0][row*8+0] doubles as mxS[row] (after mx finalize), +1 lowS, +2 highS

    const int tid = threadIdx.x;
    const int w = tid >> 6, lane = tid & 63;
    const int quad = lane >> 4, l16 = lane & 15;
    const int bid = blockIdx.x;
    const int quarter = bid & 3;
    const int qt = (bid >> 2) & 31;
    const int bh = bid >> 7;
    const int q0 = qt * TQ;
    const int k0 = quarter * KQ;
    const int b = bh >> 4;
    const bool mfull = (flags[b] == 0xFFFFFFFFu);

    // c-window: c = clip(k-q,±512)+512, width <= 287
    const int cmin = min(512, max(-512, k0 - (q0 + 31))) + 512;
    const int cmax = min(512, max(-512, k0 + 255 - q0)) + 512;
    const int rsb = cmin & ~15;   // RS storage base (16-aligned)
    const int cb0 = cmin & ~7;    // PbB storage base (16B-aligned)

    // Q A-fragments for BOTH row-tiles
    bf16x8 aq[2][2];
#pragma unroll
    for (int rt = 0; rt < 2; ++rt) {
        const unsigned short* qrow = qb + ((size_t)bh * SEQ + q0 + rt * 16 + l16) * 64;
        aq[rt][0] = *(const bf16x8*)(qrow + quad * 8);
        aq[rt][1] = *(const bf16x8*)(qrow + 32 + quad * 8);
    }

    // ---- Phase B: RS = Q @ relk^T over window (overlay in PbB); relk frag
    // loaded once, used by both row-tiles ----
    {
        const int ct_lo = cmin >> 4, ct_hi = cmax >> 4;
        for (int ct = ct_lo + w; ct <= ct_hi; ct += 8) {
            bf16x8 bf0 = *(const bf16x8*)(relkb + (size_t)(ct * 16 + l16) * 64 + quad * 8);
            bf16x8 bf1 = *(const bf16x8*)(relkb + (size_t)(ct * 16 + l16) * 64 + 32 + quad * 8);
            floatx4 r0 = {0.f, 0.f, 0.f, 0.f}, r1 = {0.f, 0.f, 0.f, 0.f};
            r0 = __builtin_amdgcn_mfma_f32_16x16x32_bf16(aq[0][0], bf0, r0, 0, 0, 0);
            r0 = __builtin_amdgcn_mfma_f32_16x16x32_bf16(aq[0][1], bf1, r0, 0, 0, 0);
            r1 = __builtin_amdgcn_mfma_f32_16x16x32_bf16(aq[1][0], bf0, r1, 0, 0, 0);
            r1 = __builtin_amdgcn_mfma_f32_16x16x32_bf16(aq[1][1], bf1, r1, 0, 0, 0);
            const int rcol = ct * 16 + l16;
            if (rcol <= cmax) {
#pragma unroll
                for (int i = 0; i < 4; ++i) {
                    PbB[(quad * 4 + i) * PBB_S + (rcol - rsb)] = f2bu(r0[i]);
                    PbB[(16 + quad * 4 + i) * PBB_S + (rcol - rsb)] = f2bu(r1[i]);
                }
            }
        }
    }
    __syncthreads();   // (1)

    // ---- Phase C: S = Q@K^T (K frag shared by both row-tiles) + RS gather ----
    const int kc = w;               // 32-col chunk
    floatx4 acc[2][2];              // [rt][tt]
#pragma unroll
    for (int rt = 0; rt < 2; ++rt)
#pragma unroll
        for (int tt = 0; tt < 2; ++tt) acc[rt][tt] = floatx4{0.f, 0.f, 0.f, 0.f};
#pragma unroll
    for (int tt = 0; tt < 2; ++tt) {
        const unsigned short* krow = kb + ((size_t)bh * SEQ + k0 + kc * 32 + tt * 16 + l16) * 64;
        bf16x8 kf0 = *(const bf16x8*)(krow + quad * 8);
        bf16x8 kf1 = *(const bf16x8*)(krow + 32 + quad * 8);
        acc[0][tt] = __builtin_amdgcn_mfma_f32_16x16x32_bf16(aq[0][0], kf0, acc[0][tt], 0, 0, 0);
        acc[0][tt] = __builtin_amdgcn_mfma_f32_16x16x32_bf16(aq[0][1], kf1, acc[0][tt], 0, 0, 0);
        acc[1][tt] = __builtin_amdgcn_mfma_f32_16x16x32_bf16(aq[1][0], kf0, acc[1][tt], 0, 0, 0);
        acc[1][tt] = __builtin_amdgcn_mfma_f32_16x16x32_bf16(aq[1][1], kf1, acc[1][tt], 0, 0, 0);
    }
    float rmax[2][4];
#pragma unroll
    for (int rt = 0; rt < 2; ++rt)
#pragma unroll
        for (int i = 0; i < 4; ++i) rmax[rt][i] = -3.0e38f;
    if (mfull) {
#pragma unroll
        for (int rt = 0; rt < 2; ++rt)
#pragma unroll
            for (int tt = 0; tt < 2; ++tt) {
                const int k = k0 + kc * 32 + tt * 16 + l16;
#pragma unroll
                for (int i = 0; i < 4; ++i) {
                    const int row = rt * 16 + quad * 4 + i;
                    const int q = q0 + row;
                    int r = min(512, max(-512, k - q)) + 512;
                    float s = acc[rt][tt][i] + b2f(PbB[row * PBB_S + (r - rsb)]);
                    acc[rt][tt][i] = s;
                    rmax[rt][i] = fmaxf(rmax[rt][i], s);
                }
            }
    } else {
#pragma unroll
        for (int rt = 0; rt < 2; ++rt)
#pragma unroll
            for (int tt = 0; tt < 2; ++tt) {
                const int k = k0 + kc * 32 + tt * 16 + l16;
#pragma unroll
                for (int i = 0; i < 4; ++i) {
                    const int row = rt * 16 + quad * 4 + i;
                    const int q = q0 + row;
                    int r = min(512, max(-512, k - q)) + 512;
                    float s = acc[rt][tt][i] + b2f(PbB[row * PBB_S + (r - rsb)]);
                    int m = mask[(size_t)b * (SEQ * SEQ) + (size_t)q * SEQ + k];
                    s = (m == 0) ? -1e20f : s;
                    acc[rt][tt][i] = s;
                    rmax[rt][i] = fmaxf(rmax[rt][i], s);
                }
            }
    }
#pragma unroll
    for (int rt = 0; rt < 2; ++rt)
#pragma unroll
        for (int i = 0; i < 4; ++i) {
#pragma unroll
            for (int o = 1; o < 16; o <<= 1)
                rmax[rt][i] = fmaxf(rmax[rt][i], __shfl_xor(rmax[rt][i], o));
        }
    if (l16 == 0) {
#pragma unroll
        for (int rt = 0; rt < 2; ++rt)
#pragma unroll
            for (int i = 0; i < 4; ++i)
                wred[0][(rt * 16 + quad * 4 + i) * 8 + kc] = rmax[rt][i];
    }
    __syncthreads();   // (2)

    // ---- zero-fill PbB (RS dead) + finalize row max into wred[0][row*8] ----
    if (tid < TQ) {
        float m = wred[0][tid * 8];
#pragma unroll
        for (int j = 1; j < 8; ++j) m = fmaxf(m, wred[0][tid * 8 + j]);
        wred[0][tid * 8] = m;   // mxS[row]
    }
    for (int g = tid; g < TQ * (PBB_S / 8); g += 512) {
        int row = g / (PBB_S / 8), j = g - row * (PBB_S / 8);
        *(uint4*)&PbB[row * PBB_S + j * 8] = make_uint4(0u, 0u, 0u, 0u);
    }
    __syncthreads();   // (3)

    // ---- Phase D: exp, sums (+ single tail), dual P store ----
    float mxr[2][4];
#pragma unroll
    for (int rt = 0; rt < 2; ++rt)
#pragma unroll
        for (int i = 0; i < 4; ++i)
            mxr[rt][i] = wred[0][(rt * 16 + quad * 4 + i) * 8];
    float ssum[2][4] = {{0.f, 0.f, 0.f, 0.f}, {0.f, 0.f, 0.f, 0.f}};
    float tail[2][4] = {{0.f, 0.f, 0.f, 0.f}, {0.f, 0.f, 0.f, 0.f}};
#pragma unroll
    for (int rt = 0; rt < 2; ++rt)
#pragma unroll
        for (int tt = 0; tt < 2; ++tt) {
            const int k = k0 + kc * 32 + tt * 16 + l16;
#pragma unroll
            for (int i = 0; i < 4; ++i) {
                const int row = rt * 16 + quad * 4 + i;
                const int q = q0 + row;
                float p = __expf(acc[rt][tt][i] - mxr[rt][i]);
                ssum[rt][i] += p;
                const int c = k - q + 512;   // unclipped
                const bool interior = ((unsigned)(c - 1) < 1023u);
                tail[rt][i] += interior ? 0.f : p;
                unsigned short pv = f2bu(p);
                PbA[row * PBA_S + (k - k0)] = pv;
                if (interior) PbB[row * PBB_S + (c - cb0)] = pv;
            }
        }
#pragma unroll
    for (int rt = 0; rt < 2; ++rt)
#pragma unroll
        for (int i = 0; i < 4; ++i) {
#pragma unroll
            for (int o = 1; o < 16; o <<= 1) {
                ssum[rt][i] += __shfl_xor(ssum[rt][i], o);
                tail[rt][i] += __shfl_xor(tail[rt][i], o);
            }
        }
    if (l16 == 0) {
#pragma unroll
        for (int rt = 0; rt < 2; ++rt)
#pragma unroll
            for (int i = 0; i < 4; ++i) {
                const int row = rt * 16 + quad * 4 + i;
                wred[1][row * 8 + kc] = ssum[rt][i];
                wred[2][row * 8 + kc] = tail[rt][i];
            }
    }
    __syncthreads();   // (4)
    if (tid < TQ) {
        float s = 0.f, t = 0.f;
#pragma unroll
        for (int j = 0; j < 8; ++j) {
            s += wred[1][tid * 8 + j];
            t += wred[2][tid * 8 + j];
        }
        const int q = q0 + tid;
        // a 256-wide window clips at most one side; pick by geometry
        wred[0][tid * 8 + 1] = (q >= k0 + 512) ? t : 0.f;   // lowS
        wred[0][tid * 8 + 2] = (q <= k0 - 257) ? t : 0.f;   // highS
        const int R = bh * SEQ + q;
        ms[(size_t)R * 4 + quarter] = make_float2(wred[0][tid * 8], s);
    }
    __syncthreads();   // (5)

    // ---- Phase F: wave (rt, dq) owns full 256-k quarter -> no Ored ----
    {
        const int rt = w & 1;
        const int dq = w >> 1;
        floatx4 accA = {0.f, 0.f, 0.f, 0.f};
        floatx4 accB = {0.f, 0.f, 0.f, 0.f};
        const unsigned short* vbase = vtb + ((size_t)bh * 64 + dq * 16 + l16) * SEQ + k0;
        const unsigned short* rbase = relvtb + (size_t)(dq * 16 + l16) * RELV_S;
#pragma unroll
        for (int it = 0; it < 8; ++it) {
            const int co = it * 32 + quad * 8;
            bf16x8 ap = *(const bf16x8*)&PbA[(rt * 16 + l16) * PBA_S + co];
            bf16x8 bv = *(const bf16x8*)(vbase + co);
            accA = __builtin_amdgcn_mfma_f32_16x16x32_bf16(ap, bv, accA, 0, 0, 0);
        }
        const int nksB = ((cmax - cb0) >> 5) + 1;
        for (int ks = 0; ks < nksB; ++ks) {
            const int co = ks * 32 + quad * 8;
            bf16x8 ar = *(const bf16x8*)&PbB[(rt * 16 + l16) * PBB_S + co];
            bf16x8 br = *(const bf16x8*)(rbase + cb0 + co);
            accB = __builtin_amdgcn_mfma_f32_16x16x32_bf16(ar, br, accB, 0, 0, 0);
        }
        const float rv0 = b2f(rbase[0]);      // relv[0][d]
        const float rv1 = b2f(rbase[1024]);   // relv[1024][d]
#pragma unroll
        for (int i = 0; i < 4; ++i) {
            const int row = rt * 16 + quad * 4 + i;
            const int R = bh * SEQ + q0 + row;
            float val = accA[i] + accB[i] +
                        wred[0][row * 8 + 1] * rv0 + wred[0][row * 8 + 2] * rv1;
            Opart[((size_t)R * 4 + quarter) * 64 + dq * 16 + l16] = __float2half(val);
        }
    }
}

// ---------------------------------------------------------------------------
// Kernel 4: combine the four k-quarters (flash-style rescale) -> aob bf16.
// ---------------------------------------------------------------------------
__global__ __launch_bounds__(256) void sa_combine_kernel(
    const __half* __restrict__ Opart, const float2* __restrict__ ms,
    unsigned short* __restrict__ aob) {
    const int tid = threadIdx.x;
    const int R = blockIdx.x * 4 + (tid >> 6);
    const int d = tid & 63;
    float2 s[4];
#pragma unroll
    for (int j = 0; j < 4; ++j) s[j] = ms[(size_t)R * 4 + j];
    float m = fmaxf(fmaxf(s[0].x, s[1].x), fmaxf(s[2].x, s[3].x));
    float a[4], denom = 0.f;
#pragma unroll
    for (int j = 0; j < 4; ++j) {
        a[j] = __expf(s[j].x - m);
        denom += s[j].y * a[j];
    }
    float inv = 1.f / denom;
    float val = 0.f;
#pragma unroll
    for (int j = 0; j < 4; ++j)
        val += __half2float(Opart[((size_t)R * 4 + j) * 64 + d]) * a[j];
    val *= inv;
    const int bh = R >> 10, q = R & 1023, b = bh >> 4, h = bh & 15;
    aob[((size_t)b * SEQ + q) * EMB + h * 64 + d] = f2bu(val);
}

// ---------------------------------------------------------------------------
// Kernel 5: FC MFMA GEMM (unchanged). out = aob @ Wfc_b^T + bfc.
// ---------------------------------------------------------------------------
__global__ __launch_bounds__(256, 2) void sa_fc_kernel(
    const unsigned short* __restrict__ A, const unsigned short* __restrict__ W,
    const float* __restrict__ bias, float* __restrict__ out) {
    const int t = threadIdx.x;
    const int w = t >> 6, lane = t & 63;
    const int quad = lane >> 4, l16 = lane & 15;
    const int mw = blockIdx.x * 64 + (w & 1) * 32;
    const int nw = blockIdx.y * 256 + (w >> 1) * 128;

    floatx4 acc[2][8];
#pragma unroll
    for (int mt = 0; mt < 2; ++mt)
#pragma unroll
        for (int j = 0; j < 8; ++j) acc[mt][j] = floatx4{0.f, 0.f, 0.f, 0.f};
    float bj[8];
#pragma unroll
    for (int j = 0; j < 8; ++j) bj[j] = bias[nw + j * 16 + l16];

    for (int ks = 0; ks < 32; ++ks) {
        const int co = ks * 32 + quad * 8;
        bf16x8 af0 = *(const bf16x8*)(A + (size_t)(mw + l16) * EMB + co);
        bf16x8 af1 = *(const bf16x8*)(A + (size_t)(mw + 16 + l16) * EMB + co);
#pragma unroll
        for (int j = 0; j < 8; ++j) {
            bf16x8 bf = *(const bf16x8*)(W + (size_t)(nw + j * 16 + l16) * EMB + co);
            acc[0][j] = __builtin_amdgcn_mfma_f32_16x16x32_bf16(af0, bf, acc[0][j], 0, 0, 0);
            acc[1][j] = __builtin_amdgcn_mfma_f32_16x16x32_bf16(af1, bf, acc[1][j], 0, 0, 0);
        }
    }
#pragma unroll
    for (int mt = 0; mt < 2; ++mt)
#pragma unroll
        for (int j = 0; j < 8; ++j) {
            const int col = nw + j * 16 + l16;
#pragma unroll
            for (int i = 0; i < 4; ++i) {
                const size_t row = mw + mt * 16 + quad * 4 + i;
                out[row * EMB + col] = acc[mt][j][i] + bj[j];
            }
        }
}

extern "C" void kernel_launch(void* const* d_in, const int* in_sizes, int n_in,
                              void* d_out, int out_size, void* d_ws, size_t ws_size,
                              hipStream_t stream) {
    const float* query = (const float*)d_in[0];
    const float* key = (const float*)d_in[1];
    const float* value = (const float*)d_in[2];
    const int* mask = (const int*)d_in[3];
    const float* Wq = (const float*)d_in[4];
    const float* bq = (const float*)d_in[5];
    const float* Wk = (const float*)d_in[6];
    const float* bk = (const float*)d_in[7];
    const float* Wv = (const float*)d_in[8];
    const float* bv = (const float*)d_in[9];
    const float* Wfc = (const float*)d_in[10];
    const float* bfc = (const float*)d_in[11];
    const float* relk = (const float*)d_in[12];
    const float* relv = (const float*)d_in[13];
    float* out = (float*)d_out;

    char* base = (char*)d_ws;
    const size_t MB = (size_t)1 << 20;
    // Layout (aob overlays qb: qb is fully consumed by attn before combine
    // writes aob; stream order guarantees safety). Total ws use ~62.6 MB.
    unsigned short* qb = (unsigned short*)(base + 0 * MB);        // 8 MB
    unsigned short* aob = qb;                                     // overlay
    unsigned short* kb = (unsigned short*)(base + 8 * MB);        // 8 MB
    unsigned short* vtb = (unsigned short*)(base + 16 * MB);      // 8 MB
    unsigned short* wfcb = (unsigned short*)(base + 24 * MB);     // 2 MB
    unsigned short* relkb = (unsigned short*)(base + 26 * MB);                 // 133,120 B
    unsigned short* relvtb = (unsigned short*)(base + 26 * MB + 163840);       // 136,192 B
    unsigned short* wqb = (unsigned short*)(base + 26 * MB + 327680);          // 8 KB each
    unsigned short* wkb = (unsigned short*)(base + 26 * MB + 335872);
    unsigned short* wvb = (unsigned short*)(base + 26 * MB + 344064);
    unsigned* flags = (unsigned*)(base + 26 * MB + 360448);                    // 16 B
    unsigned* part = (unsigned*)(base + 26 * MB + 364544);                     // 1 KB
    float2* ms = (float2*)(base + 27 * MB);                                    // 2 MB
    __half* Opart = (__half*)(base + 29 * MB);                                 // 33.5 MB

    // prep FIRST: proj consumes bf16 weights; attn consumes rel tables+flags.
    sa_prep_kernel<<<CONV_BLOCKS + 256, 256, 0, stream>>>(
        Wfc, relk, relv, Wq, Wk, Wv, mask, wfcb, relkb, relvtb, wqb, wkb, wvb, part);
    sa_proj_kernel<<<dim3(1024, 3), 256, 0, stream>>>(
        query, key, value, wqb, wkb, wvb, bq, bk, bv, qb, kb, vtb);
    sa_maskred2<<<1, 64, 0, stream>>>(part, flags);
    sa_attn_kernel<<<64 * 32 * 4, 512, 0, stream>>>(
        qb, kb, vtb, mask, relkb, relvtb, flags, Opart, ms);
    sa_combine_kernel<<<(4 * HEADS * SEQ) / 4, 256, 0, stream>>>(Opart, ms, aob);
    sa_fc_kernel<<<dim3(64, 4), 256, 0, stream>>>(aob, wfcb, bfc, out);
}